// Round 5
// baseline (309.825 us; speedup 1.0000x reference)
//
#include <hip/hip_runtime.h>

// GCNLinkPredictor: 2-layer GCN, N=100000, E=3.2M, F=128, U=1000.
// R12: fix the fusion's occupancy poisoning.
//   R11 counters: fused dispatch 90us, Occupancy 28.5% (52KB LDS union
//   charged to ALL blocks incl. 3125 fill blocks that need 12.5KB),
//   SQ_LDS_BANK_CONFLICT 1.3e7 (Wt staging: scalar fp16 writes at
//   stride 1088B = 16-way bank conflict).
//   Fix: GEMM keeps only Xs in LDS (17.4KB union). W1/W2 pre-transposed
//   to fp16 [n][k] by tiny wprep kernel; B-fragments loaded straight
//   from global — 32KB == L1 size, L1-resident per CU after first pass.
//   Kills the conflicted staging, restores fill TLP, shrinks dyn-gemm
//   LDS too. Fill blocks first in the fused grid (long pole).
// Carried: LDS bitmask flags (R10), split-phase atomics (R9), hist int4
// (R8), passthrough fused into gemm staging (R8), wave shuffle-scan
// partials (R10), gather 4-edge unrolls (R8), gemm+fill fusion (R11).

#define F_DIM 128
#define U_USERS 1000
#define SCAN_CHUNK 1024
#define NFCAP 48000     // frontier cap (expected ~33K)
#define NCHUNK 3        // node-space chunks for histogram
#define SBIN 40960      // nodes per chunk (3*40960 >= 100000)
#define SW (SBIN / 2)   // packed words per chunk (2 x u16 per word)
#define PSLICE 85       // edge slices per chunk -> 255 blocks
#define XPAD 136        // fp16 LDS row stride (128 + 8)
#define BMW 3136        // frontier bitmask words (ceil(100000/32)=3125, padded)
#define SMEM_BYTES (64 * XPAD * 2)   // 17408: Xs only (>= bitmask 12544)

using f16x8 = __attribute__((ext_vector_type(8))) _Float16;
using f16x2 = __attribute__((ext_vector_type(2))) _Float16;
using f32x4 = __attribute__((ext_vector_type(4))) float;

union H4 { uint2 u2; _Float16 h[4]; };

// ---- W pre-transpose: wt[n*128+k] = f16(W[k*128+n]), W1 then W2 ----
__global__ __launch_bounds__(128) void wprep_kernel(const float* __restrict__ W1,
                                                    const float* __restrict__ W2,
                                                    _Float16* __restrict__ wt1,
                                                    _Float16* __restrict__ wt2) {
    int nr = blockIdx.x & 127;
    const float* W = (blockIdx.x < 128) ? W1 : W2;
    _Float16* o = (blockIdx.x < 128) ? wt1 : wt2;
    int k = threadIdx.x;
    o[nr * 128 + k] = (_Float16)W[k * 128 + nr];
}

// ---- histogram: LDS packed counters, no global atomics ----
__global__ __launch_bounds__(1024) void hist_kernel(const int* __restrict__ src,
                                                    const int* __restrict__ dst,
                                                    unsigned int* __restrict__ partial,
                                                    int* __restrict__ fr, int E, int n) {
    __shared__ unsigned int h[SW];   // 80 KB
    int tid = threadIdx.x;
    int c = blockIdx.x % NCHUNK;
    int p = blockIdx.x / NCHUNK;
    for (int i = tid; i < SW; i += 1024) h[i] = 0u;
    __syncthreads();

    int lo = c * SBIN;
    int hi = lo + SBIN;
    int len = (E + PSLICE - 1) / PSLICE;
    int base = p * len;
    int end = min(E, base + len);
    int e = base + tid * 4;
    for (; e + 3 < end; e += 4096) {
        int4 dv = *(const int4*)(dst + e);
#pragma unroll
        for (int i = 0; i < 4; ++i) {
            int d = ((const int*)&dv)[i];
            if ((unsigned)d < (unsigned)n) {
                if (d >= lo && d < hi) {
                    int local = d - lo;
                    atomicAdd(&h[local >> 1], 1u << ((local & 1) << 4));
                }
                if (c == 0 && d < U_USERS) {
                    int s = src[e + i];
                    if ((unsigned)s < (unsigned)n) fr[s] = 1;
                }
            }
        }
    }
    for (; e < end; ++e) {   // tail (rare)
        int d = dst[e];
        if ((unsigned)d < (unsigned)n) {
            if (d >= lo && d < hi) {
                int local = d - lo;
                atomicAdd(&h[local >> 1], 1u << ((local & 1) << 4));
            }
            if (c == 0 && d < U_USERS) {
                int s = src[e];
                if ((unsigned)s < (unsigned)n) fr[s] = 1;
            }
        }
    }
    __syncthreads();
    unsigned int* outp = partial + ((size_t)(c * PSLICE + p)) * SW;
    for (int i = tid; i < SW; i += 1024) outp[i] = h[i];
}

// ---- reduce partials -> deg; fused prep: inv, degF, fr[i<U]=1, bitmask ----
__global__ void reduce_prep_kernel(const unsigned int* __restrict__ partial,
                                   float* __restrict__ inv, int* __restrict__ fr,
                                   int* __restrict__ degF,
                                   unsigned int* __restrict__ bitsG, int n) {
    int t = blockIdx.x * blockDim.x + threadIdx.x;
    if (t >= NCHUNK * SW) return;
    int c = t / SW, w = t % SW;
    unsigned int a0 = 0, a1 = 0;
    const unsigned int* basep = partial + (size_t)c * PSLICE * SW + w;
#pragma unroll 5
    for (int p = 0; p < PSLICE; ++p) {
        unsigned int v = basep[(size_t)p * SW];
        a0 += v & 0xFFFFu;
        a1 += v >> 16;
    }
    int i0 = c * SBIN + 2 * w;   // even
    unsigned int pair = 0u;
#pragma unroll
    for (int k = 0; k < 2; ++k) {
        int i = i0 + k;
        unsigned int dg = k ? a1 : a0;
        if (i < n) {
            inv[i] = rsqrtf((float)dg + 1.0f);
            bool isfr = (i < U_USERS) || (fr[i] != 0);
            if (i < U_USERS) fr[i] = 1;
            degF[i] = isfr ? (int)dg : 0;
            if (isfr) pair |= (1u << k);
        }
    }
    if (pair) atomicOr(&bitsG[i0 >> 5], pair << (i0 & 31));
}

// ---- dual exclusive scan (degF -> rp, fr -> remap), 3 kernels ----
__global__ void scan_reduce2_kernel(const int* __restrict__ dA, const int* __restrict__ dB,
                                    int* __restrict__ pA, int* __restrict__ pB, int n) {
    __shared__ int sdata[256];
    int b = blockIdx.x, t = threadIdx.x;
    int base = b * SCAN_CHUNK;
    int sumA = 0, sumB = 0;
#pragma unroll
    for (int i = 0; i < 4; ++i) {
        int idx = base + t + 256 * i;
        if (idx < n) { sumA += dA[idx]; sumB += dB[idx]; }
    }
    sdata[t] = sumA; __syncthreads();
    for (int s = 128; s > 0; s >>= 1) { if (t < s) sdata[t] += sdata[t + s]; __syncthreads(); }
    if (t == 0) pA[b] = sdata[0];
    __syncthreads();
    sdata[t] = sumB; __syncthreads();
    for (int s = 128; s > 0; s >>= 1) { if (t < s) sdata[t] += sdata[t + s]; __syncthreads(); }
    if (t == 0) pB[b] = sdata[0];
}

// two waves: wave0 scans pA, wave1 scans pB; nb <= 128 (nb=98)
__global__ void scan_partials2_kernel(int* __restrict__ pA, int* __restrict__ pB, int nb) {
    int wv = threadIdx.x >> 6, lane = threadIdx.x & 63;
    int* p = wv ? pB : pA;
    int i0 = lane * 2, i1 = lane * 2 + 1;
    int v0 = (i0 < nb) ? p[i0] : 0;
    int v1 = (i1 < nb) ? p[i1] : 0;
    int sum = v0 + v1;
    int incl = sum;
    for (int ofs = 1; ofs < 64; ofs <<= 1) {
        int t = __shfl_up(incl, ofs);
        if (lane >= ofs) incl += t;
    }
    int run = incl - sum;   // exclusive base for this lane's segment
    if (i0 < nb) p[i0] = run;
    if (i1 < nb) p[i1] = run + v0;
}

__global__ void scan_final2_kernel(const int* __restrict__ dA, const int* __restrict__ pA,
                                   int* __restrict__ rp,
                                   const int* __restrict__ dB, const int* __restrict__ pB,
                                   int* __restrict__ remap,
                                   int* __restrict__ flist, int* __restrict__ nf_dev, int n) {
    __shared__ int sthread[256];
    int b = blockIdx.x, t = threadIdx.x;
    int base = b * SCAN_CHUNK;
    {
        int v[4]; int sum = 0;
#pragma unroll
        for (int i = 0; i < 4; ++i) { int idx = base + 4 * t + i; v[i] = (idx < n) ? dA[idx] : 0; sum += v[i]; }
        sthread[t] = sum; __syncthreads();
        for (int ofs = 1; ofs < 256; ofs <<= 1) {
            int val = (t >= ofs) ? sthread[t - ofs] : 0;
            __syncthreads(); sthread[t] += val; __syncthreads();
        }
        int run = sthread[t] - sum + pA[b];
#pragma unroll
        for (int i = 0; i < 4; ++i) { int idx = base + 4 * t + i; if (idx < n) rp[idx] = run; run += v[i]; }
        __syncthreads();
    }
    {
        int v[4]; int sum = 0;
#pragma unroll
        for (int i = 0; i < 4; ++i) { int idx = base + 4 * t + i; v[i] = (idx < n) ? dB[idx] : 0; sum += v[i]; }
        sthread[t] = sum; __syncthreads();
        for (int ofs = 1; ofs < 256; ofs <<= 1) {
            int val = (t >= ofs) ? sthread[t - ofs] : 0;
            __syncthreads(); sthread[t] += val; __syncthreads();
        }
        int run = sthread[t] - sum + pB[b];
#pragma unroll
        for (int i = 0; i < 4; ++i) {
            int idx = base + 4 * t + i;
            if (idx < n) {
                remap[idx] = run;
                if (v[i] && run < NFCAP) flist[run] = idx;
                if (idx == n - 1) *nf_dev = min(run + v[i], NFCAP);
            }
            run += v[i];
        }
    }
}

// ---- fill_csr body: LDS bitmask flags + 4 edges/thread split-phase ----
__device__ __forceinline__ void fill_csr_body(const int* __restrict__ src,
                                              const int* __restrict__ dst,
                                              const unsigned int* __restrict__ bitsG,
                                              int* __restrict__ rp, int* __restrict__ col,
                                              int E, int n, int fblk,
                                              unsigned char* smem) {
    unsigned int* bm = (unsigned int*)smem;   // 12.5 KB of the union
    int tid = threadIdx.x;
    int nw = (n + 31) >> 5;
    for (int i = tid; i < nw; i += 256) bm[i] = bitsG[i];
    __syncthreads();

    int t = fblk * 256 + tid;
    int e0 = t * 4;
    if (e0 + 3 < E) {
        int4 dv = *(const int4*)(dst + e0);
        int4 sv = *(const int4*)(src + e0);
        const int* dp = (const int*)&dv;
        const int* sp = (const int*)&sv;
        // phase 1: 4 independent LDS bit tests (no global txns)
        bool f[4];
#pragma unroll
        for (int i = 0; i < 4; ++i) {
            int d = dp[i];
            f[i] = ((unsigned)d < (unsigned)n) && ((unsigned)sp[i] < (unsigned)n)
                   && ((bm[d >> 5] >> (d & 31)) & 1u);
        }
        // phase 2: issue all 4 atomics; results not consumed -> in flight together
        int pos[4];
#pragma unroll
        for (int i = 0; i < 4; ++i) {
            pos[i] = -1;
            if (f[i]) pos[i] = atomicAdd(&rp[dp[i]], 1);
        }
        // phase 3: one wait, 4 independent scattered stores
#pragma unroll
        for (int i = 0; i < 4; ++i) {
            if (f[i] && (unsigned)pos[i] < (unsigned)E) col[pos[i]] = sp[i];
        }
    } else {
        for (int e = e0; e < E; ++e) {
            int d = dst[e], s = src[e];
            if ((unsigned)d < (unsigned)n && (unsigned)s < (unsigned)n &&
                ((bm[d >> 5] >> (d & 31)) & 1u)) {
                int pos = atomicAdd(&rp[d], 1);
                if ((unsigned)pos < (unsigned)E) col[pos] = s;
            }
        }
    }
}

// ---- MFMA fp16 GEMM body: outh[n,128] = f16(X[n,128] @ W[128,128]) ----
// 256 threads = 4 waves, 64 rows/block. LDS: Xs fp16 [64][136] only
// (17.4KB). B-fragments read directly from pre-transposed fp16 wth
// [n][k] in global: 32KB == L1 size, L1-resident per CU.
// pout != nullptr: also store raw x rows >= U to out (fused passthrough).
__device__ __forceinline__ void gemm_mfma_body(const float* __restrict__ X,
                                               const _Float16* __restrict__ wth,
                                               _Float16* __restrict__ outh,
                                               float* __restrict__ pout,
                                               int nrows, int rowBase,
                                               unsigned char* smem) {
    _Float16* Xs = (_Float16*)smem;            // [r][k]
    int tid = threadIdx.x;

    // stage X tile fp16 row-major: 2048 float4s / 256 = 8 each
#pragma unroll
    for (int i = 0; i < 8; ++i) {
        int j = tid + 256 * i;        // j = r*32 + k4
        int r = j >> 5;
        int k4 = j & 31;
        int row = rowBase + r;
        float4 v = make_float4(0.f, 0.f, 0.f, 0.f);
        if (row < nrows) {
            v = ((const float4*)(X + (size_t)row * F_DIM))[k4];
            if (pout != nullptr && row >= U_USERS)
                ((float4*)(pout + (size_t)row * F_DIM))[k4] = v;   // fused passthrough
        }
        H4 p;
#pragma unroll
        for (int q = 0; q < 4; ++q) p.h[q] = (_Float16)((const float*)&v)[q];
        *(uint2*)&Xs[r * XPAD + k4 * 4] = p.u2;
    }
    __syncthreads();

    int w = tid >> 6;
    int lane = tid & 63;
    int m = lane & 15;
    int quad = lane >> 4;
    int R = w * 16;                   // block-local row base for this wave

    f32x4 acc[8];
#pragma unroll
    for (int i = 0; i < 8; ++i) acc[i] = (f32x4){0.f, 0.f, 0.f, 0.f};

#pragma unroll
    for (int kc = 0; kc < 4; ++kc) {
        f16x8 a = *(const f16x8*)&Xs[(R + m) * XPAD + kc * 32 + quad * 8];
#pragma unroll
        for (int ct = 0; ct < 8; ++ct) {
            f16x8 b = *(const f16x8*)&wth[(size_t)(ct * 16 + m) * F_DIM + kc * 32 + quad * 8];
            acc[ct] = __builtin_amdgcn_mfma_f32_16x16x32_f16(a, b, acc[ct], 0, 0, 0);
        }
    }

#pragma unroll
    for (int ct = 0; ct < 8; ++ct) {
#pragma unroll
        for (int reg = 0; reg < 4; ++reg) {
            int row = rowBase + R + quad * 4 + reg;
            if (row < nrows)
                outh[(size_t)row * F_DIM + ct * 16 + m] = (_Float16)acc[ct][reg];
        }
    }
}

// ---- fused dispatch: blocks [0,fillBlocks) fill_csr, rest gemm1 ----
__global__ __launch_bounds__(256) void gemm_fill_kernel(const float* __restrict__ X,
                                                        const _Float16* __restrict__ wth,
                                                        _Float16* __restrict__ outh,
                                                        float* __restrict__ pout, int nrows,
                                                        int fillBlocks,
                                                        const int* __restrict__ src,
                                                        const int* __restrict__ dst,
                                                        const unsigned int* __restrict__ bitsG,
                                                        int* __restrict__ rp,
                                                        int* __restrict__ col, int E, int n) {
    __shared__ __align__(16) unsigned char smem[SMEM_BYTES];   // 17.4 KB union
    int b = blockIdx.x;
    if (b < fillBlocks) {
        fill_csr_body(src, dst, bitsG, rp, col, E, n, b, smem);
    } else {
        gemm_mfma_body(X, wth, outh, pout, nrows, (b - fillBlocks) * 64, smem);
    }
}

__global__ __launch_bounds__(256) void gemm_f16_dyn_kernel(const float* __restrict__ X,
                                                           const _Float16* __restrict__ wth,
                                                           _Float16* __restrict__ outh,
                                                           const int* __restrict__ nrows_p) {
    __shared__ __align__(16) unsigned char smem[SMEM_BYTES];
    int nrows = *nrows_p;
    int rowBase = blockIdx.x * 64;
    if (rowBase >= nrows) return;
    gemm_mfma_body(X, wth, outh, nullptr, nrows, rowBase, smem);
}

// ---- layer-1 gather over compact frontier rows (fp16 rows, fp32 accum) ----
__global__ __launch_bounds__(256) void gather_l1_kernel(const _Float16* __restrict__ xwh,
                                                        const float* __restrict__ inv,
                                                        const int* __restrict__ rp,
                                                        const int* __restrict__ col,
                                                        const int* __restrict__ flist,
                                                        const int* __restrict__ nf_p,
                                                        const float* __restrict__ b,
                                                        float* __restrict__ h1c) {
    int ci = blockIdx.x * 4 + (threadIdx.x >> 6);
    if (ci >= *nf_p) return;
    int lane = threadIdx.x & 63;
    int node = flist[ci];
    int start = (node == 0) ? 0 : rp[node - 1];
    int end = rp[node];

    float accx = 0.f, accy = 0.f;
    for (int base = start; base < end; base += 64) {
        int j = base + lane;
        int s_l = 0; float c_l = 0.f;
        if (j < end) { s_l = col[j]; c_l = inv[s_l]; }
        int cnt = min(64, end - base);
        int i = 0;
        for (; i + 4 <= cnt; i += 4) {
            int s0 = __shfl(s_l, i + 0); float f0 = __shfl(c_l, i + 0);
            int s1 = __shfl(s_l, i + 1); float f1 = __shfl(c_l, i + 1);
            int s2 = __shfl(s_l, i + 2); float f2 = __shfl(c_l, i + 2);
            int s3 = __shfl(s_l, i + 3); float f3 = __shfl(c_l, i + 3);
            f16x2 v0 = ((const f16x2*)(xwh + (size_t)s0 * F_DIM))[lane];
            f16x2 v1 = ((const f16x2*)(xwh + (size_t)s1 * F_DIM))[lane];
            f16x2 v2 = ((const f16x2*)(xwh + (size_t)s2 * F_DIM))[lane];
            f16x2 v3 = ((const f16x2*)(xwh + (size_t)s3 * F_DIM))[lane];
            accx += (float)v0[0] * f0 + (float)v1[0] * f1 + (float)v2[0] * f2 + (float)v3[0] * f3;
            accy += (float)v0[1] * f0 + (float)v1[1] * f1 + (float)v2[1] * f2 + (float)v3[1] * f3;
        }
        for (; i < cnt; ++i) {
            int s0 = __shfl(s_l, i); float f0 = __shfl(c_l, i);
            f16x2 v0 = ((const f16x2*)(xwh + (size_t)s0 * F_DIM))[lane];
            accx += (float)v0[0] * f0;
            accy += (float)v0[1] * f0;
        }
    }

    float ivd = inv[node];
    f16x2 self = ((const f16x2*)(xwh + (size_t)node * F_DIM))[lane];
    float vx = accx * ivd + (float)self[0] * ivd * ivd + b[lane * 2];
    float vy = accy * ivd + (float)self[1] * ivd * ivd + b[lane * 2 + 1];
    vx = vx > 0.f ? vx : expf(vx) - 1.f;
    vy = vy > 0.f ? vy : expf(vy) - 1.f;
    ((float2*)(h1c + (size_t)ci * F_DIM))[lane] = make_float2(vx, vy);
}

// ---- layer-2 gather over rows [0,U) (fp16 compact rows) ----
__global__ __launch_bounds__(256) void gather_l2_kernel(const _Float16* __restrict__ xwc,
                                                        const float* __restrict__ inv,
                                                        const int* __restrict__ rp,
                                                        const int* __restrict__ col,
                                                        const int* __restrict__ remap,
                                                        const float* __restrict__ b,
                                                        float* __restrict__ out) {
    int node = blockIdx.x * 4 + (threadIdx.x >> 6);
    if (node >= U_USERS) return;
    int lane = threadIdx.x & 63;
    int start = (node == 0) ? 0 : rp[node - 1];
    int end = rp[node];

    float accx = 0.f, accy = 0.f;
    for (int base = start; base < end; base += 64) {
        int j = base + lane;
        int r_l = 0; float c_l = 0.f;
        if (j < end) { int s = col[j]; c_l = inv[s]; r_l = remap[s]; }
        int cnt = min(64, end - base);
        int i = 0;
        for (; i + 4 <= cnt; i += 4) {
            int r0 = __shfl(r_l, i + 0); float f0 = __shfl(c_l, i + 0);
            int r1 = __shfl(r_l, i + 1); float f1 = __shfl(c_l, i + 1);
            int r2 = __shfl(r_l, i + 2); float f2 = __shfl(c_l, i + 2);
            int r3 = __shfl(r_l, i + 3); float f3 = __shfl(c_l, i + 3);
            f16x2 v0 = ((const f16x2*)(xwc + (size_t)r0 * F_DIM))[lane];
            f16x2 v1 = ((const f16x2*)(xwc + (size_t)r1 * F_DIM))[lane];
            f16x2 v2 = ((const f16x2*)(xwc + (size_t)r2 * F_DIM))[lane];
            f16x2 v3 = ((const f16x2*)(xwc + (size_t)r3 * F_DIM))[lane];
            accx += (float)v0[0] * f0 + (float)v1[0] * f1 + (float)v2[0] * f2 + (float)v3[0] * f3;
            accy += (float)v0[1] * f0 + (float)v1[1] * f1 + (float)v2[1] * f2 + (float)v3[1] * f3;
        }
        for (; i < cnt; ++i) {
            int rr = __shfl(r_l, i); float f0 = __shfl(c_l, i);
            f16x2 v0 = ((const f16x2*)(xwc + (size_t)rr * F_DIM))[lane];
            accx += (float)v0[0] * f0;
            accy += (float)v0[1] * f0;
        }
    }

    float ivd = inv[node];
    f16x2 self = ((const f16x2*)(xwc + (size_t)node * F_DIM))[lane];  // remap[node]==node for node<U
    float vx = accx * ivd + (float)self[0] * ivd * ivd + b[lane * 2];
    float vy = accy * ivd + (float)self[1] * ivd * ivd + b[lane * 2 + 1];
    vx = vx > 0.f ? vx : expf(vx) - 1.f;
    vy = vy > 0.f ? vy : expf(vy) - 1.f;
    ((float2*)(out + (size_t)node * F_DIM))[lane] = make_float2(vx, vy);
}

extern "C" void kernel_launch(void* const* d_in, const int* in_sizes, int n_in,
                              void* d_out, int out_size, void* d_ws, size_t ws_size,
                              hipStream_t stream) {
    const float* x  = (const float*)d_in[0];
    const int*   ei = (const int*)d_in[1];   // [2, E] int32
    const float* W1 = (const float*)d_in[2];
    const float* b1 = (const float*)d_in[3];
    const float* W2 = (const float*)d_in[4];
    const float* b2 = (const float*)d_in[5];
    float* out = (float*)d_out;

    int n = in_sizes[0] / F_DIM;   // 100000
    int E = in_sizes[1] / 2;       // 3200000
    const int* srcI = ei;
    const int* dstI = ei + E;

    // workspace layout (~90 MB)
    _Float16* xwh = (_Float16*)d_ws;                 // n*128 halfs (xw1 / xwc, 25.6MB)
    float* h1c   = (float*)(xwh + (size_t)n * F_DIM);// NFCAP*128 f (24.6MB)
    float* inv   = h1c + (size_t)NFCAP * F_DIM;      // n f
    int* fr      = (int*)(inv + n);                  // n
    int* degF    = fr + n;                           // n
    int* remap   = degF + n;                         // n
    int* rp      = remap + n;                        // n
    int* flist   = rp + n;                           // NFCAP
    int* pA      = flist + NFCAP;                    // 1024
    int* pB      = pA + 1024;                        // 1024
    int* nf_dev  = pB + 1024;                        // 1 (+pad)
    int* col     = nf_dev + 16;                      // E
    unsigned int* partialH = (unsigned int*)(col + E);  // NCHUNK*PSLICE*SW
    unsigned int* bitsG = partialH + (size_t)NCHUNK * PSLICE * SW;  // BMW words
    _Float16* wt1h = (_Float16*)(bitsG + BMW);       // 16384 halfs (32KB)
    _Float16* wt2h = wt1h + 16384;                   // 16384 halfs (32KB)

    int nb = (n + SCAN_CHUNK - 1) / SCAN_CHUNK;      // 98

    hipMemsetAsync(fr, 0, (size_t)n * sizeof(int), stream);
    hipMemsetAsync(bitsG, 0, (size_t)BMW * sizeof(unsigned int), stream);

    wprep_kernel<<<256, 128, 0, stream>>>(W1, W2, wt1h, wt2h);

    hist_kernel<<<NCHUNK * PSLICE, 1024, 0, stream>>>(srcI, dstI, partialH, fr, E, n);
    reduce_prep_kernel<<<(NCHUNK * SW + 255) / 256, 256, 0, stream>>>(partialH, inv, fr, degF, bitsG, n);

    scan_reduce2_kernel<<<nb, 256, 0, stream>>>(degF, fr, pA, pB, n);
    scan_partials2_kernel<<<1, 128, 0, stream>>>(pA, pB, nb);
    scan_final2_kernel<<<nb, 256, 0, stream>>>(degF, pA, rp, fr, pB, remap, flist, nf_dev, n);

    // fused: fill blocks first (long pole), gemm1 blocks backfill.
    int fillBlocks = (E / 4 + 255) / 256;    // 3125
    int gemmBlocks = (n + 63) / 64;          // 1563
    gemm_fill_kernel<<<fillBlocks + gemmBlocks, 256, 0, stream>>>(
        x, wt1h, xwh, out, n, fillBlocks, srcI, dstI, bitsG, rp, col, E, n);

    gather_l1_kernel<<<(NFCAP + 3) / 4, 256, 0, stream>>>(xwh, inv, rp, col, flist, nf_dev, b1, h1c);

    // layer 2: compact MFMA GEMM (nf rows), gather over U rows
    gemm_f16_dyn_kernel<<<(NFCAP + 63) / 64, 256, 0, stream>>>(h1c, wt2h, xwh, nf_dev);
    gather_l2_kernel<<<(U_USERS + 3) / 4, 256, 0, stream>>>(xwh, inv, rp, col, remap, b2, out);
}

// Round 6
// 296.901 us; speedup vs baseline: 1.0435x; 1.0435x over previous
//
#include <hip/hip_runtime.h>

// GCNLinkPredictor: 2-layer GCN, N=100000, E=3.2M, F=128, U=1000.
// R13: flip R12's LDS assignment.
//   R12 regressed (104us fused): B-fragments from global put L2 latency
//   in the MFMA inner loop (X staging thrashes L1, wth never resident).
//   Correct split: W (reused by all 4688 blocks) lives in LDS; X
//   (streamed once) is read straight to registers as A-fragments, and
//   the passthrough stores come from those same registers.
//   Wt layout: [128][128] halfs, 8-half group g of row n stored at
//   g^(n&15). Staging (task = (n,k8), coalesced fp32 reads, one 16B
//   LDS write) and MFMA b-reads are both bank-balanced (8 words/bank).
//   Union = 32KB -> 5 blocks/CU for BOTH paths (R11 was 3), no Xs
//   barrier, no wprep kernel.
// Carried: gemm+fill fusion, fill-first (R11/R12), LDS bitmask flags
// (R10), split-phase atomics (R9), hist int4 (R8), passthrough fusion
// (R8), wave shuffle-scan partials (R10), gather 4-edge unrolls (R8).

#define F_DIM 128
#define U_USERS 1000
#define SCAN_CHUNK 1024
#define NFCAP 48000     // frontier cap (expected ~33K)
#define NCHUNK 3        // node-space chunks for histogram
#define SBIN 40960      // nodes per chunk (3*40960 >= 100000)
#define SW (SBIN / 2)   // packed words per chunk (2 x u16 per word)
#define PSLICE 85       // edge slices per chunk -> 255 blocks
#define XPAD 136        // (unused by gemm now; kept for reference)
#define BMW 3136        // frontier bitmask words (ceil(100000/32)=3125, padded)
#define SMEM_BYTES 32768   // Wt [128][128] fp16 (>= bitmask 12544)

using f16x8 = __attribute__((ext_vector_type(8))) _Float16;
using f16x2 = __attribute__((ext_vector_type(2))) _Float16;
using f32x4 = __attribute__((ext_vector_type(4))) float;

// ---- histogram: LDS packed counters, no global atomics ----
__global__ __launch_bounds__(1024) void hist_kernel(const int* __restrict__ src,
                                                    const int* __restrict__ dst,
                                                    unsigned int* __restrict__ partial,
                                                    int* __restrict__ fr, int E, int n) {
    __shared__ unsigned int h[SW];   // 80 KB
    int tid = threadIdx.x;
    int c = blockIdx.x % NCHUNK;
    int p = blockIdx.x / NCHUNK;
    for (int i = tid; i < SW; i += 1024) h[i] = 0u;
    __syncthreads();

    int lo = c * SBIN;
    int hi = lo + SBIN;
    int len = (E + PSLICE - 1) / PSLICE;
    int base = p * len;
    int end = min(E, base + len);
    int e = base + tid * 4;
    for (; e + 3 < end; e += 4096) {
        int4 dv = *(const int4*)(dst + e);
#pragma unroll
        for (int i = 0; i < 4; ++i) {
            int d = ((const int*)&dv)[i];
            if ((unsigned)d < (unsigned)n) {
                if (d >= lo && d < hi) {
                    int local = d - lo;
                    atomicAdd(&h[local >> 1], 1u << ((local & 1) << 4));
                }
                if (c == 0 && d < U_USERS) {
                    int s = src[e + i];
                    if ((unsigned)s < (unsigned)n) fr[s] = 1;
                }
            }
        }
    }
    for (; e < end; ++e) {   // tail (rare)
        int d = dst[e];
        if ((unsigned)d < (unsigned)n) {
            if (d >= lo && d < hi) {
                int local = d - lo;
                atomicAdd(&h[local >> 1], 1u << ((local & 1) << 4));
            }
            if (c == 0 && d < U_USERS) {
                int s = src[e];
                if ((unsigned)s < (unsigned)n) fr[s] = 1;
            }
        }
    }
    __syncthreads();
    unsigned int* outp = partial + ((size_t)(c * PSLICE + p)) * SW;
    for (int i = tid; i < SW; i += 1024) outp[i] = h[i];
}

// ---- reduce partials -> deg; fused prep: inv, degF, fr[i<U]=1, bitmask ----
__global__ void reduce_prep_kernel(const unsigned int* __restrict__ partial,
                                   float* __restrict__ inv, int* __restrict__ fr,
                                   int* __restrict__ degF,
                                   unsigned int* __restrict__ bitsG, int n) {
    int t = blockIdx.x * blockDim.x + threadIdx.x;
    if (t >= NCHUNK * SW) return;
    int c = t / SW, w = t % SW;
    unsigned int a0 = 0, a1 = 0;
    const unsigned int* basep = partial + (size_t)c * PSLICE * SW + w;
#pragma unroll 5
    for (int p = 0; p < PSLICE; ++p) {
        unsigned int v = basep[(size_t)p * SW];
        a0 += v & 0xFFFFu;
        a1 += v >> 16;
    }
    int i0 = c * SBIN + 2 * w;   // even
    unsigned int pair = 0u;
#pragma unroll
    for (int k = 0; k < 2; ++k) {
        int i = i0 + k;
        unsigned int dg = k ? a1 : a0;
        if (i < n) {
            inv[i] = rsqrtf((float)dg + 1.0f);
            bool isfr = (i < U_USERS) || (fr[i] != 0);
            if (i < U_USERS) fr[i] = 1;
            degF[i] = isfr ? (int)dg : 0;
            if (isfr) pair |= (1u << k);
        }
    }
    if (pair) atomicOr(&bitsG[i0 >> 5], pair << (i0 & 31));
}

// ---- dual exclusive scan (degF -> rp, fr -> remap), 3 kernels ----
__global__ void scan_reduce2_kernel(const int* __restrict__ dA, const int* __restrict__ dB,
                                    int* __restrict__ pA, int* __restrict__ pB, int n) {
    __shared__ int sdata[256];
    int b = blockIdx.x, t = threadIdx.x;
    int base = b * SCAN_CHUNK;
    int sumA = 0, sumB = 0;
#pragma unroll
    for (int i = 0; i < 4; ++i) {
        int idx = base + t + 256 * i;
        if (idx < n) { sumA += dA[idx]; sumB += dB[idx]; }
    }
    sdata[t] = sumA; __syncthreads();
    for (int s = 128; s > 0; s >>= 1) { if (t < s) sdata[t] += sdata[t + s]; __syncthreads(); }
    if (t == 0) pA[b] = sdata[0];
    __syncthreads();
    sdata[t] = sumB; __syncthreads();
    for (int s = 128; s > 0; s >>= 1) { if (t < s) sdata[t] += sdata[t + s]; __syncthreads(); }
    if (t == 0) pB[b] = sdata[0];
}

// two waves: wave0 scans pA, wave1 scans pB; nb <= 128 (nb=98)
__global__ void scan_partials2_kernel(int* __restrict__ pA, int* __restrict__ pB, int nb) {
    int wv = threadIdx.x >> 6, lane = threadIdx.x & 63;
    int* p = wv ? pB : pA;
    int i0 = lane * 2, i1 = lane * 2 + 1;
    int v0 = (i0 < nb) ? p[i0] : 0;
    int v1 = (i1 < nb) ? p[i1] : 0;
    int sum = v0 + v1;
    int incl = sum;
    for (int ofs = 1; ofs < 64; ofs <<= 1) {
        int t = __shfl_up(incl, ofs);
        if (lane >= ofs) incl += t;
    }
    int run = incl - sum;   // exclusive base for this lane's segment
    if (i0 < nb) p[i0] = run;
    if (i1 < nb) p[i1] = run + v0;
}

__global__ void scan_final2_kernel(const int* __restrict__ dA, const int* __restrict__ pA,
                                   int* __restrict__ rp,
                                   const int* __restrict__ dB, const int* __restrict__ pB,
                                   int* __restrict__ remap,
                                   int* __restrict__ flist, int* __restrict__ nf_dev, int n) {
    __shared__ int sthread[256];
    int b = blockIdx.x, t = threadIdx.x;
    int base = b * SCAN_CHUNK;
    {
        int v[4]; int sum = 0;
#pragma unroll
        for (int i = 0; i < 4; ++i) { int idx = base + 4 * t + i; v[i] = (idx < n) ? dA[idx] : 0; sum += v[i]; }
        sthread[t] = sum; __syncthreads();
        for (int ofs = 1; ofs < 256; ofs <<= 1) {
            int val = (t >= ofs) ? sthread[t - ofs] : 0;
            __syncthreads(); sthread[t] += val; __syncthreads();
        }
        int run = sthread[t] - sum + pA[b];
#pragma unroll
        for (int i = 0; i < 4; ++i) { int idx = base + 4 * t + i; if (idx < n) rp[idx] = run; run += v[i]; }
        __syncthreads();
    }
    {
        int v[4]; int sum = 0;
#pragma unroll
        for (int i = 0; i < 4; ++i) { int idx = base + 4 * t + i; v[i] = (idx < n) ? dB[idx] : 0; sum += v[i]; }
        sthread[t] = sum; __syncthreads();
        for (int ofs = 1; ofs < 256; ofs <<= 1) {
            int val = (t >= ofs) ? sthread[t - ofs] : 0;
            __syncthreads(); sthread[t] += val; __syncthreads();
        }
        int run = sthread[t] - sum + pB[b];
#pragma unroll
        for (int i = 0; i < 4; ++i) {
            int idx = base + 4 * t + i;
            if (idx < n) {
                remap[idx] = run;
                if (v[i] && run < NFCAP) flist[run] = idx;
                if (idx == n - 1) *nf_dev = min(run + v[i], NFCAP);
            }
            run += v[i];
        }
    }
}

// ---- fill_csr body: LDS bitmask flags + 4 edges/thread split-phase ----
__device__ __forceinline__ void fill_csr_body(const int* __restrict__ src,
                                              const int* __restrict__ dst,
                                              const unsigned int* __restrict__ bitsG,
                                              int* __restrict__ rp, int* __restrict__ col,
                                              int E, int n, int fblk,
                                              unsigned char* smem) {
    unsigned int* bm = (unsigned int*)smem;   // 12.5 KB of the union
    int tid = threadIdx.x;
    int nw = (n + 31) >> 5;
    for (int i = tid; i < nw; i += 256) bm[i] = bitsG[i];
    __syncthreads();

    int t = fblk * 256 + tid;
    int e0 = t * 4;
    if (e0 + 3 < E) {
        int4 dv = *(const int4*)(dst + e0);
        int4 sv = *(const int4*)(src + e0);
        const int* dp = (const int*)&dv;
        const int* sp = (const int*)&sv;
        // phase 1: 4 independent LDS bit tests (no global txns)
        bool f[4];
#pragma unroll
        for (int i = 0; i < 4; ++i) {
            int d = dp[i];
            f[i] = ((unsigned)d < (unsigned)n) && ((unsigned)sp[i] < (unsigned)n)
                   && ((bm[d >> 5] >> (d & 31)) & 1u);
        }
        // phase 2: issue all 4 atomics; results not consumed -> in flight together
        int pos[4];
#pragma unroll
        for (int i = 0; i < 4; ++i) {
            pos[i] = -1;
            if (f[i]) pos[i] = atomicAdd(&rp[dp[i]], 1);
        }
        // phase 3: one wait, 4 independent scattered stores
#pragma unroll
        for (int i = 0; i < 4; ++i) {
            if (f[i] && (unsigned)pos[i] < (unsigned)E) col[pos[i]] = sp[i];
        }
    } else {
        for (int e = e0; e < E; ++e) {
            int d = dst[e], s = src[e];
            if ((unsigned)d < (unsigned)n && (unsigned)s < (unsigned)n &&
                ((bm[d >> 5] >> (d & 31)) & 1u)) {
                int pos = atomicAdd(&rp[d], 1);
                if ((unsigned)pos < (unsigned)E) col[pos] = s;
            }
        }
    }
}

// ---- MFMA fp16 GEMM body: outh[n,128] = f16(X[n,128] @ W[128,128]) ----
// 256 threads = 4 waves, 64 rows/block. LDS: Wt only — [128][128] fp16,
// 8-half group g of row n stored at g^(n&15) (bank-balanced staging and
// b-reads). A-fragments read directly from global X (each byte once per
// block); passthrough (rows >= U -> pout) stores from the same regs.
__device__ __forceinline__ void gemm_mfma_body(const float* __restrict__ X,
                                               const float* __restrict__ W,
                                               _Float16* __restrict__ outh,
                                               float* __restrict__ pout,
                                               int nrows, int rowBase,
                                               unsigned char* smem) {
    _Float16* Wt = (_Float16*)smem;            // [128][128], swizzled groups
    int tid = threadIdx.x;

    // stage W: 2048 tasks (nr, k8), 8 per thread; coalesced fp32 reads,
    // one conflict-free 16B LDS write each.
#pragma unroll
    for (int i = 0; i < 8; ++i) {
        int j = tid + 256 * i;        // 0..2047
        int nr = j & 127;
        int k8 = j >> 7;              // 0..15
        f16x8 v;
#pragma unroll
        for (int kk = 0; kk < 8; ++kk)
            v[kk] = (_Float16)W[(k8 * 8 + kk) * F_DIM + nr];
        *(f16x8*)&Wt[nr * F_DIM + ((k8 ^ (nr & 15)) * 8)] = v;
    }
    __syncthreads();

    int w = tid >> 6;
    int lane = tid & 63;
    int m = lane & 15;
    int quad = lane >> 4;
    int row = rowBase + w * 16 + m;
    bool rv = row < nrows;

    // A-fragments: 8 floats per kc straight from global, convert to fp16.
    f16x8 a0, a1, a2, a3;
    {
        const float* xr = X + (size_t)row * F_DIM;
        float* pr = (pout != nullptr && rv && row >= U_USERS)
                        ? pout + (size_t)row * F_DIM : nullptr;
#pragma unroll
        for (int kc = 0; kc < 4; ++kc) {
            float4 lo = make_float4(0.f, 0.f, 0.f, 0.f);
            float4 hi = lo;
            if (rv) {
                lo = ((const float4*)(xr + kc * 32 + quad * 8))[0];
                hi = ((const float4*)(xr + kc * 32 + quad * 8))[1];
            }
            if (pr) {
                ((float4*)(pr + kc * 32 + quad * 8))[0] = lo;
                ((float4*)(pr + kc * 32 + quad * 8))[1] = hi;
            }
            f16x8 av;
            av[0] = (_Float16)lo.x; av[1] = (_Float16)lo.y;
            av[2] = (_Float16)lo.z; av[3] = (_Float16)lo.w;
            av[4] = (_Float16)hi.x; av[5] = (_Float16)hi.y;
            av[6] = (_Float16)hi.z; av[7] = (_Float16)hi.w;
            if (kc == 0) a0 = av; else if (kc == 1) a1 = av;
            else if (kc == 2) a2 = av; else a3 = av;
        }
    }

    f32x4 acc[8];
#pragma unroll
    for (int i = 0; i < 8; ++i) acc[i] = (f32x4){0.f, 0.f, 0.f, 0.f};

#pragma unroll
    for (int kc = 0; kc < 4; ++kc) {
        f16x8 a = (kc == 0) ? a0 : (kc == 1) ? a1 : (kc == 2) ? a2 : a3;
#pragma unroll
        for (int ct = 0; ct < 8; ++ct) {
            f16x8 b = *(const f16x8*)&Wt[(ct * 16 + m) * F_DIM +
                                         (((kc * 4 + quad) ^ m) * 8)];
            acc[ct] = __builtin_amdgcn_mfma_f32_16x16x32_f16(a, b, acc[ct], 0, 0, 0);
        }
    }

#pragma unroll
    for (int ct = 0; ct < 8; ++ct) {
#pragma unroll
        for (int reg = 0; reg < 4; ++reg) {
            int r = rowBase + w * 16 + quad * 4 + reg;
            if (r < nrows)
                outh[(size_t)r * F_DIM + ct * 16 + m] = (_Float16)acc[ct][reg];
        }
    }
}

// ---- fused dispatch: blocks [0,fillBlocks) fill_csr, rest gemm1 ----
__global__ __launch_bounds__(256) void gemm_fill_kernel(const float* __restrict__ X,
                                                        const float* __restrict__ W,
                                                        _Float16* __restrict__ outh,
                                                        float* __restrict__ pout, int nrows,
                                                        int fillBlocks,
                                                        const int* __restrict__ src,
                                                        const int* __restrict__ dst,
                                                        const unsigned int* __restrict__ bitsG,
                                                        int* __restrict__ rp,
                                                        int* __restrict__ col, int E, int n) {
    __shared__ __align__(16) unsigned char smem[SMEM_BYTES];   // 32 KB union
    int b = blockIdx.x;
    if (b < fillBlocks) {
        fill_csr_body(src, dst, bitsG, rp, col, E, n, b, smem);
    } else {
        gemm_mfma_body(X, W, outh, pout, nrows, (b - fillBlocks) * 64, smem);
    }
}

__global__ __launch_bounds__(256) void gemm_f16_dyn_kernel(const float* __restrict__ X,
                                                           const float* __restrict__ W,
                                                           _Float16* __restrict__ outh,
                                                           const int* __restrict__ nrows_p) {
    __shared__ __align__(16) unsigned char smem[SMEM_BYTES];
    int nrows = *nrows_p;
    int rowBase = blockIdx.x * 64;
    if (rowBase >= nrows) return;
    gemm_mfma_body(X, W, outh, nullptr, nrows, rowBase, smem);
}

// ---- layer-1 gather over compact frontier rows (fp16 rows, fp32 accum) ----
__global__ __launch_bounds__(256) void gather_l1_kernel(const _Float16* __restrict__ xwh,
                                                        const float* __restrict__ inv,
                                                        const int* __restrict__ rp,
                                                        const int* __restrict__ col,
                                                        const int* __restrict__ flist,
                                                        const int* __restrict__ nf_p,
                                                        const float* __restrict__ b,
                                                        float* __restrict__ h1c) {
    int ci = blockIdx.x * 4 + (threadIdx.x >> 6);
    if (ci >= *nf_p) return;
    int lane = threadIdx.x & 63;
    int node = flist[ci];
    int start = (node == 0) ? 0 : rp[node - 1];
    int end = rp[node];

    float accx = 0.f, accy = 0.f;
    for (int base = start; base < end; base += 64) {
        int j = base + lane;
        int s_l = 0; float c_l = 0.f;
        if (j < end) { s_l = col[j]; c_l = inv[s_l]; }
        int cnt = min(64, end - base);
        int i = 0;
        for (; i + 4 <= cnt; i += 4) {
            int s0 = __shfl(s_l, i + 0); float f0 = __shfl(c_l, i + 0);
            int s1 = __shfl(s_l, i + 1); float f1 = __shfl(c_l, i + 1);
            int s2 = __shfl(s_l, i + 2); float f2 = __shfl(c_l, i + 2);
            int s3 = __shfl(s_l, i + 3); float f3 = __shfl(c_l, i + 3);
            f16x2 v0 = ((const f16x2*)(xwh + (size_t)s0 * F_DIM))[lane];
            f16x2 v1 = ((const f16x2*)(xwh + (size_t)s1 * F_DIM))[lane];
            f16x2 v2 = ((const f16x2*)(xwh + (size_t)s2 * F_DIM))[lane];
            f16x2 v3 = ((const f16x2*)(xwh + (size_t)s3 * F_DIM))[lane];
            accx += (float)v0[0] * f0 + (float)v1[0] * f1 + (float)v2[0] * f2 + (float)v3[0] * f3;
            accy += (float)v0[1] * f0 + (float)v1[1] * f1 + (float)v2[1] * f2 + (float)v3[1] * f3;
        }
        for (; i < cnt; ++i) {
            int s0 = __shfl(s_l, i); float f0 = __shfl(c_l, i);
            f16x2 v0 = ((const f16x2*)(xwh + (size_t)s0 * F_DIM))[lane];
            accx += (float)v0[0] * f0;
            accy += (float)v0[1] * f0;
        }
    }

    float ivd = inv[node];
    f16x2 self = ((const f16x2*)(xwh + (size_t)node * F_DIM))[lane];
    float vx = accx * ivd + (float)self[0] * ivd * ivd + b[lane * 2];
    float vy = accy * ivd + (float)self[1] * ivd * ivd + b[lane * 2 + 1];
    vx = vx > 0.f ? vx : expf(vx) - 1.f;
    vy = vy > 0.f ? vy : expf(vy) - 1.f;
    ((float2*)(h1c + (size_t)ci * F_DIM))[lane] = make_float2(vx, vy);
}

// ---- layer-2 gather over rows [0,U) (fp16 compact rows) ----
__global__ __launch_bounds__(256) void gather_l2_kernel(const _Float16* __restrict__ xwc,
                                                        const float* __restrict__ inv,
                                                        const int* __restrict__ rp,
                                                        const int* __restrict__ col,
                                                        const int* __restrict__ remap,
                                                        const float* __restrict__ b,
                                                        float* __restrict__ out) {
    int node = blockIdx.x * 4 + (threadIdx.x >> 6);
    if (node >= U_USERS) return;
    int lane = threadIdx.x & 63;
    int start = (node == 0) ? 0 : rp[node - 1];
    int end = rp[node];

    float accx = 0.f, accy = 0.f;
    for (int base = start; base < end; base += 64) {
        int j = base + lane;
        int r_l = 0; float c_l = 0.f;
        if (j < end) { int s = col[j]; c_l = inv[s]; r_l = remap[s]; }
        int cnt = min(64, end - base);
        int i = 0;
        for (; i + 4 <= cnt; i += 4) {
            int r0 = __shfl(r_l, i + 0); float f0 = __shfl(c_l, i + 0);
            int r1 = __shfl(r_l, i + 1); float f1 = __shfl(c_l, i + 1);
            int r2 = __shfl(r_l, i + 2); float f2 = __shfl(c_l, i + 2);
            int r3 = __shfl(r_l, i + 3); float f3 = __shfl(c_l, i + 3);
            f16x2 v0 = ((const f16x2*)(xwc + (size_t)r0 * F_DIM))[lane];
            f16x2 v1 = ((const f16x2*)(xwc + (size_t)r1 * F_DIM))[lane];
            f16x2 v2 = ((const f16x2*)(xwc + (size_t)r2 * F_DIM))[lane];
            f16x2 v3 = ((const f16x2*)(xwc + (size_t)r3 * F_DIM))[lane];
            accx += (float)v0[0] * f0 + (float)v1[0] * f1 + (float)v2[0] * f2 + (float)v3[0] * f3;
            accy += (float)v0[1] * f0 + (float)v1[1] * f1 + (float)v2[1] * f2 + (float)v3[1] * f3;
        }
        for (; i < cnt; ++i) {
            int rr = __shfl(r_l, i); float f0 = __shfl(c_l, i);
            f16x2 v0 = ((const f16x2*)(xwc + (size_t)rr * F_DIM))[lane];
            accx += (float)v0[0] * f0;
            accy += (float)v0[1] * f0;
        }
    }

    float ivd = inv[node];
    f16x2 self = ((const f16x2*)(xwc + (size_t)node * F_DIM))[lane];  // remap[node]==node for node<U
    float vx = accx * ivd + (float)self[0] * ivd * ivd + b[lane * 2];
    float vy = accy * ivd + (float)self[1] * ivd * ivd + b[lane * 2 + 1];
    vx = vx > 0.f ? vx : expf(vx) - 1.f;
    vy = vy > 0.f ? vy : expf(vy) - 1.f;
    ((float2*)(out + (size_t)node * F_DIM))[lane] = make_float2(vx, vy);
}

extern "C" void kernel_launch(void* const* d_in, const int* in_sizes, int n_in,
                              void* d_out, int out_size, void* d_ws, size_t ws_size,
                              hipStream_t stream) {
    const float* x  = (const float*)d_in[0];
    const int*   ei = (const int*)d_in[1];   // [2, E] int32
    const float* W1 = (const float*)d_in[2];
    const float* b1 = (const float*)d_in[3];
    const float* W2 = (const float*)d_in[4];
    const float* b2 = (const float*)d_in[5];
    float* out = (float*)d_out;

    int n = in_sizes[0] / F_DIM;   // 100000
    int E = in_sizes[1] / 2;       // 3200000
    const int* srcI = ei;
    const int* dstI = ei + E;

    // workspace layout (~90 MB)
    _Float16* xwh = (_Float16*)d_ws;                 // n*128 halfs (xw1 / xwc, 25.6MB)
    float* h1c   = (float*)(xwh + (size_t)n * F_DIM);// NFCAP*128 f (24.6MB)
    float* inv   = h1c + (size_t)NFCAP * F_DIM;      // n f
    int* fr      = (int*)(inv + n);                  // n
    int* degF    = fr + n;                           // n
    int* remap   = degF + n;                         // n
    int* rp      = remap + n;                        // n
    int* flist   = rp + n;                           // NFCAP
    int* pA      = flist + NFCAP;                    // 1024
    int* pB      = pA + 1024;                        // 1024
    int* nf_dev  = pB + 1024;                        // 1 (+pad)
    int* col     = nf_dev + 16;                      // E
    unsigned int* partialH = (unsigned int*)(col + E);  // NCHUNK*PSLICE*SW
    unsigned int* bitsG = partialH + (size_t)NCHUNK * PSLICE * SW;  // BMW words

    int nb = (n + SCAN_CHUNK - 1) / SCAN_CHUNK;      // 98

    hipMemsetAsync(fr, 0, (size_t)n * sizeof(int), stream);
    hipMemsetAsync(bitsG, 0, (size_t)BMW * sizeof(unsigned int), stream);

    hist_kernel<<<NCHUNK * PSLICE, 1024, 0, stream>>>(srcI, dstI, partialH, fr, E, n);
    reduce_prep_kernel<<<(NCHUNK * SW + 255) / 256, 256, 0, stream>>>(partialH, inv, fr, degF, bitsG, n);

    scan_reduce2_kernel<<<nb, 256, 0, stream>>>(degF, fr, pA, pB, n);
    scan_partials2_kernel<<<1, 128, 0, stream>>>(pA, pB, nb);
    scan_final2_kernel<<<nb, 256, 0, stream>>>(degF, pA, rp, fr, pB, remap, flist, nf_dev, n);

    // fused: fill blocks first (long pole), gemm1 blocks backfill.
    int fillBlocks = (E / 4 + 255) / 256;    // 3125
    int gemmBlocks = (n + 63) / 64;          // 1563
    gemm_fill_kernel<<<fillBlocks + gemmBlocks, 256, 0, stream>>>(
        x, W1, xwh, out, n, fillBlocks, srcI, dstI, bitsG, rp, col, E, n);

    gather_l1_kernel<<<(NFCAP + 3) / 4, 256, 0, stream>>>(xwh, inv, rp, col, flist, nf_dev, b1, h1c);

    // layer 2: compact MFMA GEMM (nf rows), gather over U rows
    gemm_f16_dyn_kernel<<<(NFCAP + 63) / 64, 256, 0, stream>>>(h1c, W2, xwh, nf_dev);
    gather_l2_kernel<<<(U_USERS + 3) / 4, 256, 0, stream>>>(xwh, inv, rp, col, remap, b2, out);
}

// Round 7
// 284.836 us; speedup vs baseline: 1.0877x; 1.0424x over previous
//
#include <hip/hip_runtime.h>

// GCNLinkPredictor: 2-layer GCN, N=100000, E=3.2M, F=128, U=1000.
// R14: interleave the fused roles (the actual overlap fix).
//   R11/R13 evidence: concatenated block ranges give ~ZERO overlap --
//   blocks dispatch in blockIdx order, so the two ranges run nearly
//   serially inside one dispatch (fused 90/110us vs serial sum 88).
//   Fix: Bresenham role interleave -- block b is a gemm block iff
//   floor((b+1)*g/T) > floor(b*g/T). Every CU then holds a mix of
//   scatter-latency (fill) and MFMA/stream (gemm) blocks at all times;
//   separate pipes => time ~= max, not sum (m114).
// Carried: Wt-in-LDS swizzled gemm, X->regs A-fragments (R13), LDS
// bitmask flags (R10), split-phase atomics (R9), hist int4 (R8),
// passthrough fusion (R8), wave shuffle-scan partials (R10), gather
// 4-edge unrolls (R8).

#define F_DIM 128
#define U_USERS 1000
#define SCAN_CHUNK 1024
#define NFCAP 48000     // frontier cap (expected ~33K)
#define NCHUNK 3        // node-space chunks for histogram
#define SBIN 40960      // nodes per chunk (3*40960 >= 100000)
#define SW (SBIN / 2)   // packed words per chunk (2 x u16 per word)
#define PSLICE 85       // edge slices per chunk -> 255 blocks
#define BMW 3136        // frontier bitmask words (ceil(100000/32)=3125, padded)
#define SMEM_BYTES 32768   // Wt [128][128] fp16 (>= bitmask 12544)

using f16x8 = __attribute__((ext_vector_type(8))) _Float16;
using f16x2 = __attribute__((ext_vector_type(2))) _Float16;
using f32x4 = __attribute__((ext_vector_type(4))) float;

// ---- histogram: LDS packed counters, no global atomics ----
__global__ __launch_bounds__(1024) void hist_kernel(const int* __restrict__ src,
                                                    const int* __restrict__ dst,
                                                    unsigned int* __restrict__ partial,
                                                    int* __restrict__ fr, int E, int n) {
    __shared__ unsigned int h[SW];   // 80 KB
    int tid = threadIdx.x;
    int c = blockIdx.x % NCHUNK;
    int p = blockIdx.x / NCHUNK;
    for (int i = tid; i < SW; i += 1024) h[i] = 0u;
    __syncthreads();

    int lo = c * SBIN;
    int hi = lo + SBIN;
    int len = (E + PSLICE - 1) / PSLICE;
    int base = p * len;
    int end = min(E, base + len);
    int e = base + tid * 4;
    for (; e + 3 < end; e += 4096) {
        int4 dv = *(const int4*)(dst + e);
#pragma unroll
        for (int i = 0; i < 4; ++i) {
            int d = ((const int*)&dv)[i];
            if ((unsigned)d < (unsigned)n) {
                if (d >= lo && d < hi) {
                    int local = d - lo;
                    atomicAdd(&h[local >> 1], 1u << ((local & 1) << 4));
                }
                if (c == 0 && d < U_USERS) {
                    int s = src[e + i];
                    if ((unsigned)s < (unsigned)n) fr[s] = 1;
                }
            }
        }
    }
    for (; e < end; ++e) {   // tail (rare)
        int d = dst[e];
        if ((unsigned)d < (unsigned)n) {
            if (d >= lo && d < hi) {
                int local = d - lo;
                atomicAdd(&h[local >> 1], 1u << ((local & 1) << 4));
            }
            if (c == 0 && d < U_USERS) {
                int s = src[e];
                if ((unsigned)s < (unsigned)n) fr[s] = 1;
            }
        }
    }
    __syncthreads();
    unsigned int* outp = partial + ((size_t)(c * PSLICE + p)) * SW;
    for (int i = tid; i < SW; i += 1024) outp[i] = h[i];
}

// ---- reduce partials -> deg; fused prep: inv, degF, fr[i<U]=1, bitmask ----
__global__ void reduce_prep_kernel(const unsigned int* __restrict__ partial,
                                   float* __restrict__ inv, int* __restrict__ fr,
                                   int* __restrict__ degF,
                                   unsigned int* __restrict__ bitsG, int n) {
    int t = blockIdx.x * blockDim.x + threadIdx.x;
    if (t >= NCHUNK * SW) return;
    int c = t / SW, w = t % SW;
    unsigned int a0 = 0, a1 = 0;
    const unsigned int* basep = partial + (size_t)c * PSLICE * SW + w;
#pragma unroll 5
    for (int p = 0; p < PSLICE; ++p) {
        unsigned int v = basep[(size_t)p * SW];
        a0 += v & 0xFFFFu;
        a1 += v >> 16;
    }
    int i0 = c * SBIN + 2 * w;   // even
    unsigned int pair = 0u;
#pragma unroll
    for (int k = 0; k < 2; ++k) {
        int i = i0 + k;
        unsigned int dg = k ? a1 : a0;
        if (i < n) {
            inv[i] = rsqrtf((float)dg + 1.0f);
            bool isfr = (i < U_USERS) || (fr[i] != 0);
            if (i < U_USERS) fr[i] = 1;
            degF[i] = isfr ? (int)dg : 0;
            if (isfr) pair |= (1u << k);
        }
    }
    if (pair) atomicOr(&bitsG[i0 >> 5], pair << (i0 & 31));
}

// ---- dual exclusive scan (degF -> rp, fr -> remap), 3 kernels ----
__global__ void scan_reduce2_kernel(const int* __restrict__ dA, const int* __restrict__ dB,
                                    int* __restrict__ pA, int* __restrict__ pB, int n) {
    __shared__ int sdata[256];
    int b = blockIdx.x, t = threadIdx.x;
    int base = b * SCAN_CHUNK;
    int sumA = 0, sumB = 0;
#pragma unroll
    for (int i = 0; i < 4; ++i) {
        int idx = base + t + 256 * i;
        if (idx < n) { sumA += dA[idx]; sumB += dB[idx]; }
    }
    sdata[t] = sumA; __syncthreads();
    for (int s = 128; s > 0; s >>= 1) { if (t < s) sdata[t] += sdata[t + s]; __syncthreads(); }
    if (t == 0) pA[b] = sdata[0];
    __syncthreads();
    sdata[t] = sumB; __syncthreads();
    for (int s = 128; s > 0; s >>= 1) { if (t < s) sdata[t] += sdata[t + s]; __syncthreads(); }
    if (t == 0) pB[b] = sdata[0];
}

// two waves: wave0 scans pA, wave1 scans pB; nb <= 128 (nb=98)
__global__ void scan_partials2_kernel(int* __restrict__ pA, int* __restrict__ pB, int nb) {
    int wv = threadIdx.x >> 6, lane = threadIdx.x & 63;
    int* p = wv ? pB : pA;
    int i0 = lane * 2, i1 = lane * 2 + 1;
    int v0 = (i0 < nb) ? p[i0] : 0;
    int v1 = (i1 < nb) ? p[i1] : 0;
    int sum = v0 + v1;
    int incl = sum;
    for (int ofs = 1; ofs < 64; ofs <<= 1) {
        int t = __shfl_up(incl, ofs);
        if (lane >= ofs) incl += t;
    }
    int run = incl - sum;   // exclusive base for this lane's segment
    if (i0 < nb) p[i0] = run;
    if (i1 < nb) p[i1] = run + v0;
}

__global__ void scan_final2_kernel(const int* __restrict__ dA, const int* __restrict__ pA,
                                   int* __restrict__ rp,
                                   const int* __restrict__ dB, const int* __restrict__ pB,
                                   int* __restrict__ remap,
                                   int* __restrict__ flist, int* __restrict__ nf_dev, int n) {
    __shared__ int sthread[256];
    int b = blockIdx.x, t = threadIdx.x;
    int base = b * SCAN_CHUNK;
    {
        int v[4]; int sum = 0;
#pragma unroll
        for (int i = 0; i < 4; ++i) { int idx = base + 4 * t + i; v[i] = (idx < n) ? dA[idx] : 0; sum += v[i]; }
        sthread[t] = sum; __syncthreads();
        for (int ofs = 1; ofs < 256; ofs <<= 1) {
            int val = (t >= ofs) ? sthread[t - ofs] : 0;
            __syncthreads(); sthread[t] += val; __syncthreads();
        }
        int run = sthread[t] - sum + pA[b];
#pragma unroll
        for (int i = 0; i < 4; ++i) { int idx = base + 4 * t + i; if (idx < n) rp[idx] = run; run += v[i]; }
        __syncthreads();
    }
    {
        int v[4]; int sum = 0;
#pragma unroll
        for (int i = 0; i < 4; ++i) { int idx = base + 4 * t + i; v[i] = (idx < n) ? dB[idx] : 0; sum += v[i]; }
        sthread[t] = sum; __syncthreads();
        for (int ofs = 1; ofs < 256; ofs <<= 1) {
            int val = (t >= ofs) ? sthread[t - ofs] : 0;
            __syncthreads(); sthread[t] += val; __syncthreads();
        }
        int run = sthread[t] - sum + pB[b];
#pragma unroll
        for (int i = 0; i < 4; ++i) {
            int idx = base + 4 * t + i;
            if (idx < n) {
                remap[idx] = run;
                if (v[i] && run < NFCAP) flist[run] = idx;
                if (idx == n - 1) *nf_dev = min(run + v[i], NFCAP);
            }
            run += v[i];
        }
    }
}

// ---- fill_csr body: LDS bitmask flags + 4 edges/thread split-phase ----
__device__ __forceinline__ void fill_csr_body(const int* __restrict__ src,
                                              const int* __restrict__ dst,
                                              const unsigned int* __restrict__ bitsG,
                                              int* __restrict__ rp, int* __restrict__ col,
                                              int E, int n, int fblk,
                                              unsigned char* smem) {
    unsigned int* bm = (unsigned int*)smem;   // 12.5 KB of the union
    int tid = threadIdx.x;
    int nw = (n + 31) >> 5;
    for (int i = tid; i < nw; i += 256) bm[i] = bitsG[i];
    __syncthreads();

    int t = fblk * 256 + tid;
    int e0 = t * 4;
    if (e0 + 3 < E) {
        int4 dv = *(const int4*)(dst + e0);
        int4 sv = *(const int4*)(src + e0);
        const int* dp = (const int*)&dv;
        const int* sp = (const int*)&sv;
        // phase 1: 4 independent LDS bit tests (no global txns)
        bool f[4];
#pragma unroll
        for (int i = 0; i < 4; ++i) {
            int d = dp[i];
            f[i] = ((unsigned)d < (unsigned)n) && ((unsigned)sp[i] < (unsigned)n)
                   && ((bm[d >> 5] >> (d & 31)) & 1u);
        }
        // phase 2: issue all 4 atomics; results not consumed -> in flight together
        int pos[4];
#pragma unroll
        for (int i = 0; i < 4; ++i) {
            pos[i] = -1;
            if (f[i]) pos[i] = atomicAdd(&rp[dp[i]], 1);
        }
        // phase 3: one wait, 4 independent scattered stores
#pragma unroll
        for (int i = 0; i < 4; ++i) {
            if (f[i] && (unsigned)pos[i] < (unsigned)E) col[pos[i]] = sp[i];
        }
    } else {
        for (int e = e0; e < E; ++e) {
            int d = dst[e], s = src[e];
            if ((unsigned)d < (unsigned)n && (unsigned)s < (unsigned)n &&
                ((bm[d >> 5] >> (d & 31)) & 1u)) {
                int pos = atomicAdd(&rp[d], 1);
                if ((unsigned)pos < (unsigned)E) col[pos] = s;
            }
        }
    }
}

// ---- MFMA fp16 GEMM body: outh[n,128] = f16(X[n,128] @ W[128,128]) ----
// 256 threads = 4 waves, 64 rows/block. LDS: Wt only — [128][128] fp16,
// 8-half group g of row n stored at g^(n&15) (bank-balanced staging and
// b-reads). A-fragments read directly from global X (each byte once per
// block); passthrough (rows >= U -> pout) stores from the same regs.
__device__ __forceinline__ void gemm_mfma_body(const float* __restrict__ X,
                                               const float* __restrict__ W,
                                               _Float16* __restrict__ outh,
                                               float* __restrict__ pout,
                                               int nrows, int rowBase,
                                               unsigned char* smem) {
    _Float16* Wt = (_Float16*)smem;            // [128][128], swizzled groups
    int tid = threadIdx.x;

    // stage W: 2048 tasks (nr, k8), 8 per thread; coalesced fp32 reads,
    // one conflict-free 16B LDS write each.
#pragma unroll
    for (int i = 0; i < 8; ++i) {
        int j = tid + 256 * i;        // 0..2047
        int nr = j & 127;
        int k8 = j >> 7;              // 0..15
        f16x8 v;
#pragma unroll
        for (int kk = 0; kk < 8; ++kk)
            v[kk] = (_Float16)W[(k8 * 8 + kk) * F_DIM + nr];
        *(f16x8*)&Wt[nr * F_DIM + ((k8 ^ (nr & 15)) * 8)] = v;
    }
    __syncthreads();

    int w = tid >> 6;
    int lane = tid & 63;
    int m = lane & 15;
    int quad = lane >> 4;
    int row = rowBase + w * 16 + m;
    bool rv = row < nrows;

    // A-fragments: 8 floats per kc straight from global, convert to fp16.
    f16x8 a0, a1, a2, a3;
    {
        const float* xr = X + (size_t)row * F_DIM;
        float* pr = (pout != nullptr && rv && row >= U_USERS)
                        ? pout + (size_t)row * F_DIM : nullptr;
#pragma unroll
        for (int kc = 0; kc < 4; ++kc) {
            float4 lo = make_float4(0.f, 0.f, 0.f, 0.f);
            float4 hi = lo;
            if (rv) {
                lo = ((const float4*)(xr + kc * 32 + quad * 8))[0];
                hi = ((const float4*)(xr + kc * 32 + quad * 8))[1];
            }
            if (pr) {
                ((float4*)(pr + kc * 32 + quad * 8))[0] = lo;
                ((float4*)(pr + kc * 32 + quad * 8))[1] = hi;
            }
            f16x8 av;
            av[0] = (_Float16)lo.x; av[1] = (_Float16)lo.y;
            av[2] = (_Float16)lo.z; av[3] = (_Float16)lo.w;
            av[4] = (_Float16)hi.x; av[5] = (_Float16)hi.y;
            av[6] = (_Float16)hi.z; av[7] = (_Float16)hi.w;
            if (kc == 0) a0 = av; else if (kc == 1) a1 = av;
            else if (kc == 2) a2 = av; else a3 = av;
        }
    }

    f32x4 acc[8];
#pragma unroll
    for (int i = 0; i < 8; ++i) acc[i] = (f32x4){0.f, 0.f, 0.f, 0.f};

#pragma unroll
    for (int kc = 0; kc < 4; ++kc) {
        f16x8 a = (kc == 0) ? a0 : (kc == 1) ? a1 : (kc == 2) ? a2 : a3;
#pragma unroll
        for (int ct = 0; ct < 8; ++ct) {
            f16x8 b = *(const f16x8*)&Wt[(ct * 16 + m) * F_DIM +
                                         (((kc * 4 + quad) ^ m) * 8)];
            acc[ct] = __builtin_amdgcn_mfma_f32_16x16x32_f16(a, b, acc[ct], 0, 0, 0);
        }
    }

#pragma unroll
    for (int ct = 0; ct < 8; ++ct) {
#pragma unroll
        for (int reg = 0; reg < 4; ++reg) {
            int r = rowBase + w * 16 + quad * 4 + reg;
            if (r < nrows)
                outh[(size_t)r * F_DIM + ct * 16 + m] = (_Float16)acc[ct][reg];
        }
    }
}

// ---- fused dispatch: Bresenham-interleaved roles ----
// block b is a gemm block iff floor((b+1)*g/T) > floor(b*g/T); gemm idx
// = floor(b*g/T), fill idx = b - gemm-count-before. Even mix on every CU.
__global__ __launch_bounds__(256) void gemm_fill_kernel(const float* __restrict__ X,
                                                        const float* __restrict__ W,
                                                        _Float16* __restrict__ outh,
                                                        float* __restrict__ pout, int nrows,
                                                        int gemmBlocks, int totalBlocks,
                                                        const int* __restrict__ src,
                                                        const int* __restrict__ dst,
                                                        const unsigned int* __restrict__ bitsG,
                                                        int* __restrict__ rp,
                                                        int* __restrict__ col, int E, int n) {
    __shared__ __align__(16) unsigned char smem[SMEM_BYTES];   // 32 KB union
    int b = blockIdx.x;
    long long g = gemmBlocks, T = totalBlocks;
    int before = (int)((long long)b * g / T);        // gemm blocks in [0,b)
    int after  = (int)(((long long)b + 1) * g / T);
    if (after > before) {
        gemm_mfma_body(X, W, outh, pout, nrows, before * 64, smem);
    } else {
        fill_csr_body(src, dst, bitsG, rp, col, E, n, b - before, smem);
    }
}

__global__ __launch_bounds__(256) void gemm_f16_dyn_kernel(const float* __restrict__ X,
                                                           const float* __restrict__ W,
                                                           _Float16* __restrict__ outh,
                                                           const int* __restrict__ nrows_p) {
    __shared__ __align__(16) unsigned char smem[SMEM_BYTES];
    int nrows = *nrows_p;
    int rowBase = blockIdx.x * 64;
    if (rowBase >= nrows) return;
    gemm_mfma_body(X, W, outh, nullptr, nrows, rowBase, smem);
}

// ---- layer-1 gather over compact frontier rows (fp16 rows, fp32 accum) ----
__global__ __launch_bounds__(256) void gather_l1_kernel(const _Float16* __restrict__ xwh,
                                                        const float* __restrict__ inv,
                                                        const int* __restrict__ rp,
                                                        const int* __restrict__ col,
                                                        const int* __restrict__ flist,
                                                        const int* __restrict__ nf_p,
                                                        const float* __restrict__ b,
                                                        float* __restrict__ h1c) {
    int ci = blockIdx.x * 4 + (threadIdx.x >> 6);
    if (ci >= *nf_p) return;
    int lane = threadIdx.x & 63;
    int node = flist[ci];
    int start = (node == 0) ? 0 : rp[node - 1];
    int end = rp[node];

    float accx = 0.f, accy = 0.f;
    for (int base = start; base < end; base += 64) {
        int j = base + lane;
        int s_l = 0; float c_l = 0.f;
        if (j < end) { s_l = col[j]; c_l = inv[s_l]; }
        int cnt = min(64, end - base);
        int i = 0;
        for (; i + 4 <= cnt; i += 4) {
            int s0 = __shfl(s_l, i + 0); float f0 = __shfl(c_l, i + 0);
            int s1 = __shfl(s_l, i + 1); float f1 = __shfl(c_l, i + 1);
            int s2 = __shfl(s_l, i + 2); float f2 = __shfl(c_l, i + 2);
            int s3 = __shfl(s_l, i + 3); float f3 = __shfl(c_l, i + 3);
            f16x2 v0 = ((const f16x2*)(xwh + (size_t)s0 * F_DIM))[lane];
            f16x2 v1 = ((const f16x2*)(xwh + (size_t)s1 * F_DIM))[lane];
            f16x2 v2 = ((const f16x2*)(xwh + (size_t)s2 * F_DIM))[lane];
            f16x2 v3 = ((const f16x2*)(xwh + (size_t)s3 * F_DIM))[lane];
            accx += (float)v0[0] * f0 + (float)v1[0] * f1 + (float)v2[0] * f2 + (float)v3[0] * f3;
            accy += (float)v0[1] * f0 + (float)v1[1] * f1 + (float)v2[1] * f2 + (float)v3[1] * f3;
        }
        for (; i < cnt; ++i) {
            int s0 = __shfl(s_l, i); float f0 = __shfl(c_l, i);
            f16x2 v0 = ((const f16x2*)(xwh + (size_t)s0 * F_DIM))[lane];
            accx += (float)v0[0] * f0;
            accy += (float)v0[1] * f0;
        }
    }

    float ivd = inv[node];
    f16x2 self = ((const f16x2*)(xwh + (size_t)node * F_DIM))[lane];
    float vx = accx * ivd + (float)self[0] * ivd * ivd + b[lane * 2];
    float vy = accy * ivd + (float)self[1] * ivd * ivd + b[lane * 2 + 1];
    vx = vx > 0.f ? vx : expf(vx) - 1.f;
    vy = vy > 0.f ? vy : expf(vy) - 1.f;
    ((float2*)(h1c + (size_t)ci * F_DIM))[lane] = make_float2(vx, vy);
}

// ---- layer-2 gather over rows [0,U) (fp16 compact rows) ----
__global__ __launch_bounds__(256) void gather_l2_kernel(const _Float16* __restrict__ xwc,
                                                        const float* __restrict__ inv,
                                                        const int* __restrict__ rp,
                                                        const int* __restrict__ col,
                                                        const int* __restrict__ remap,
                                                        const float* __restrict__ b,
                                                        float* __restrict__ out) {
    int node = blockIdx.x * 4 + (threadIdx.x >> 6);
    if (node >= U_USERS) return;
    int lane = threadIdx.x & 63;
    int start = (node == 0) ? 0 : rp[node - 1];
    int end = rp[node];

    float accx = 0.f, accy = 0.f;
    for (int base = start; base < end; base += 64) {
        int j = base + lane;
        int r_l = 0; float c_l = 0.f;
        if (j < end) { int s = col[j]; c_l = inv[s]; r_l = remap[s]; }
        int cnt = min(64, end - base);
        int i = 0;
        for (; i + 4 <= cnt; i += 4) {
            int r0 = __shfl(r_l, i + 0); float f0 = __shfl(c_l, i + 0);
            int r1 = __shfl(r_l, i + 1); float f1 = __shfl(c_l, i + 1);
            int r2 = __shfl(r_l, i + 2); float f2 = __shfl(c_l, i + 2);
            int r3 = __shfl(r_l, i + 3); float f3 = __shfl(c_l, i + 3);
            f16x2 v0 = ((const f16x2*)(xwc + (size_t)r0 * F_DIM))[lane];
            f16x2 v1 = ((const f16x2*)(xwc + (size_t)r1 * F_DIM))[lane];
            f16x2 v2 = ((const f16x2*)(xwc + (size_t)r2 * F_DIM))[lane];
            f16x2 v3 = ((const f16x2*)(xwc + (size_t)r3 * F_DIM))[lane];
            accx += (float)v0[0] * f0 + (float)v1[0] * f1 + (float)v2[0] * f2 + (float)v3[0] * f3;
            accy += (float)v0[1] * f0 + (float)v1[1] * f1 + (float)v2[1] * f2 + (float)v3[1] * f3;
        }
        for (; i < cnt; ++i) {
            int rr = __shfl(r_l, i); float f0 = __shfl(c_l, i);
            f16x2 v0 = ((const f16x2*)(xwc + (size_t)rr * F_DIM))[lane];
            accx += (float)v0[0] * f0;
            accy += (float)v0[1] * f0;
        }
    }

    float ivd = inv[node];
    f16x2 self = ((const f16x2*)(xwc + (size_t)node * F_DIM))[lane];  // remap[node]==node for node<U
    float vx = accx * ivd + (float)self[0] * ivd * ivd + b[lane * 2];
    float vy = accy * ivd + (float)self[1] * ivd * ivd + b[lane * 2 + 1];
    vx = vx > 0.f ? vx : expf(vx) - 1.f;
    vy = vy > 0.f ? vy : expf(vy) - 1.f;
    ((float2*)(out + (size_t)node * F_DIM))[lane] = make_float2(vx, vy);
}

extern "C" void kernel_launch(void* const* d_in, const int* in_sizes, int n_in,
                              void* d_out, int out_size, void* d_ws, size_t ws_size,
                              hipStream_t stream) {
    const float* x  = (const float*)d_in[0];
    const int*   ei = (const int*)d_in[1];   // [2, E] int32
    const float* W1 = (const float*)d_in[2];
    const float* b1 = (const float*)d_in[3];
    const float* W2 = (const float*)d_in[4];
    const float* b2 = (const float*)d_in[5];
    float* out = (float*)d_out;

    int n = in_sizes[0] / F_DIM;   // 100000
    int E = in_sizes[1] / 2;       // 3200000
    const int* srcI = ei;
    const int* dstI = ei + E;

    // workspace layout (~90 MB)
    _Float16* xwh = (_Float16*)d_ws;                 // n*128 halfs (xw1 / xwc, 25.6MB)
    float* h1c   = (float*)(xwh + (size_t)n * F_DIM);// NFCAP*128 f (24.6MB)
    float* inv   = h1c + (size_t)NFCAP * F_DIM;      // n f
    int* fr      = (int*)(inv + n);                  // n
    int* degF    = fr + n;                           // n
    int* remap   = degF + n;                         // n
    int* rp      = remap + n;                        // n
    int* flist   = rp + n;                           // NFCAP
    int* pA      = flist + NFCAP;                    // 1024
    int* pB      = pA + 1024;                        // 1024
    int* nf_dev  = pB + 1024;                        // 1 (+pad)
    int* col     = nf_dev + 16;                      // E
    unsigned int* partialH = (unsigned int*)(col + E);  // NCHUNK*PSLICE*SW
    unsigned int* bitsG = partialH + (size_t)NCHUNK * PSLICE * SW;  // BMW words

    int nb = (n + SCAN_CHUNK - 1) / SCAN_CHUNK;      // 98

    hipMemsetAsync(fr, 0, (size_t)n * sizeof(int), stream);
    hipMemsetAsync(bitsG, 0, (size_t)BMW * sizeof(unsigned int), stream);

    hist_kernel<<<NCHUNK * PSLICE, 1024, 0, stream>>>(srcI, dstI, partialH, fr, E, n);
    reduce_prep_kernel<<<(NCHUNK * SW + 255) / 256, 256, 0, stream>>>(partialH, inv, fr, degF, bitsG, n);

    scan_reduce2_kernel<<<nb, 256, 0, stream>>>(degF, fr, pA, pB, n);
    scan_partials2_kernel<<<1, 128, 0, stream>>>(pA, pB, nb);
    scan_final2_kernel<<<nb, 256, 0, stream>>>(degF, pA, rp, fr, pB, remap, flist, nf_dev, n);

    // fused, role-interleaved: every CU holds a mix of fill (scatter
    // latency) and gemm (MFMA/stream) blocks at all times.
    int fillBlocks = (E / 4 + 255) / 256;    // 3125
    int gemmBlocks = (n + 63) / 64;          // 1563
    gemm_fill_kernel<<<fillBlocks + gemmBlocks, 256, 0, stream>>>(
        x, W1, xwh, out, n, gemmBlocks, fillBlocks + gemmBlocks,
        srcI, dstI, bitsG, rp, col, E, n);

    gather_l1_kernel<<<(NFCAP + 3) / 4, 256, 0, stream>>>(xwh, inv, rp, col, flist, nf_dev, b1, h1c);

    // layer 2: compact MFMA GEMM (nf rows), gather over U rows
    gemm_f16_dyn_kernel<<<(NFCAP + 63) / 64, 256, 0, stream>>>(h1c, W2, xwh, nf_dev);
    gather_l2_kernel<<<(U_USERS + 3) / 4, 256, 0, stream>>>(xwh, inv, rp, col, remap, b2, out);
}

// Round 8
// 279.459 us; speedup vs baseline: 1.1087x; 1.0192x over previous
//
#include <hip/hip_runtime.h>

// GCNLinkPredictor: 2-layer GCN, N=100000, E=3.2M, F=128, U=1000.
// R15: attack the hidden 196us (non-top-5 dispatches).
//   R14 verdict: fused gemm+fill = 89us == serial sum; kept as-is (no
//   more fusion rounds). Remaining time is gathers/hist/dyn-gemm.
//   (a) gather_l1/l2: 8-way MLP inner unroll (was 4) -- the broadcast
//       row-reads are latency-bound random 256B reads; double the
//       in-flight count per wave.
//   (b) h1c stored fp16 (same rounding as gemm2's old staging convert,
//       zero accuracy delta); new fp16-input gemm body for layer 2
//       loads A-fragments as one f16x8 (16B) per kc straight from
//       global. Halves h1c write+read traffic.
// Carried: role-interleaved gemm+fill fusion (R14), Wt-in-LDS swizzled
// gemm + X->regs (R13), LDS bitmask flags (R10), split-phase atomics
// (R9), hist int4 (R8), passthrough fusion (R8), wave shuffle-scan
// partials (R10).

#define F_DIM 128
#define U_USERS 1000
#define SCAN_CHUNK 1024
#define NFCAP 48000     // frontier cap (expected ~33K)
#define NCHUNK 3        // node-space chunks for histogram
#define SBIN 40960      // nodes per chunk (3*40960 >= 100000)
#define SW (SBIN / 2)   // packed words per chunk (2 x u16 per word)
#define PSLICE 85       // edge slices per chunk -> 255 blocks
#define BMW 3136        // frontier bitmask words (ceil(100000/32)=3125, padded)
#define SMEM_BYTES 32768   // Wt [128][128] fp16 (>= bitmask 12544)

using f16x8 = __attribute__((ext_vector_type(8))) _Float16;
using f16x2 = __attribute__((ext_vector_type(2))) _Float16;
using f32x4 = __attribute__((ext_vector_type(4))) float;

// ---- histogram: LDS packed counters, no global atomics ----
__global__ __launch_bounds__(1024) void hist_kernel(const int* __restrict__ src,
                                                    const int* __restrict__ dst,
                                                    unsigned int* __restrict__ partial,
                                                    int* __restrict__ fr, int E, int n) {
    __shared__ unsigned int h[SW];   // 80 KB
    int tid = threadIdx.x;
    int c = blockIdx.x % NCHUNK;
    int p = blockIdx.x / NCHUNK;
    for (int i = tid; i < SW; i += 1024) h[i] = 0u;
    __syncthreads();

    int lo = c * SBIN;
    int hi = lo + SBIN;
    int len = (E + PSLICE - 1) / PSLICE;
    int base = p * len;
    int end = min(E, base + len);
    int e = base + tid * 4;
    for (; e + 3 < end; e += 4096) {
        int4 dv = *(const int4*)(dst + e);
#pragma unroll
        for (int i = 0; i < 4; ++i) {
            int d = ((const int*)&dv)[i];
            if ((unsigned)d < (unsigned)n) {
                if (d >= lo && d < hi) {
                    int local = d - lo;
                    atomicAdd(&h[local >> 1], 1u << ((local & 1) << 4));
                }
                if (c == 0 && d < U_USERS) {
                    int s = src[e + i];
                    if ((unsigned)s < (unsigned)n) fr[s] = 1;
                }
            }
        }
    }
    for (; e < end; ++e) {   // tail (rare)
        int d = dst[e];
        if ((unsigned)d < (unsigned)n) {
            if (d >= lo && d < hi) {
                int local = d - lo;
                atomicAdd(&h[local >> 1], 1u << ((local & 1) << 4));
            }
            if (c == 0 && d < U_USERS) {
                int s = src[e];
                if ((unsigned)s < (unsigned)n) fr[s] = 1;
            }
        }
    }
    __syncthreads();
    unsigned int* outp = partial + ((size_t)(c * PSLICE + p)) * SW;
    for (int i = tid; i < SW; i += 1024) outp[i] = h[i];
}

// ---- reduce partials -> deg; fused prep: inv, degF, fr[i<U]=1, bitmask ----
__global__ void reduce_prep_kernel(const unsigned int* __restrict__ partial,
                                   float* __restrict__ inv, int* __restrict__ fr,
                                   int* __restrict__ degF,
                                   unsigned int* __restrict__ bitsG, int n) {
    int t = blockIdx.x * blockDim.x + threadIdx.x;
    if (t >= NCHUNK * SW) return;
    int c = t / SW, w = t % SW;
    unsigned int a0 = 0, a1 = 0;
    const unsigned int* basep = partial + (size_t)c * PSLICE * SW + w;
#pragma unroll 5
    for (int p = 0; p < PSLICE; ++p) {
        unsigned int v = basep[(size_t)p * SW];
        a0 += v & 0xFFFFu;
        a1 += v >> 16;
    }
    int i0 = c * SBIN + 2 * w;   // even
    unsigned int pair = 0u;
#pragma unroll
    for (int k = 0; k < 2; ++k) {
        int i = i0 + k;
        unsigned int dg = k ? a1 : a0;
        if (i < n) {
            inv[i] = rsqrtf((float)dg + 1.0f);
            bool isfr = (i < U_USERS) || (fr[i] != 0);
            if (i < U_USERS) fr[i] = 1;
            degF[i] = isfr ? (int)dg : 0;
            if (isfr) pair |= (1u << k);
        }
    }
    if (pair) atomicOr(&bitsG[i0 >> 5], pair << (i0 & 31));
}

// ---- dual exclusive scan (degF -> rp, fr -> remap), 3 kernels ----
__global__ void scan_reduce2_kernel(const int* __restrict__ dA, const int* __restrict__ dB,
                                    int* __restrict__ pA, int* __restrict__ pB, int n) {
    __shared__ int sdata[256];
    int b = blockIdx.x, t = threadIdx.x;
    int base = b * SCAN_CHUNK;
    int sumA = 0, sumB = 0;
#pragma unroll
    for (int i = 0; i < 4; ++i) {
        int idx = base + t + 256 * i;
        if (idx < n) { sumA += dA[idx]; sumB += dB[idx]; }
    }
    sdata[t] = sumA; __syncthreads();
    for (int s = 128; s > 0; s >>= 1) { if (t < s) sdata[t] += sdata[t + s]; __syncthreads(); }
    if (t == 0) pA[b] = sdata[0];
    __syncthreads();
    sdata[t] = sumB; __syncthreads();
    for (int s = 128; s > 0; s >>= 1) { if (t < s) sdata[t] += sdata[t + s]; __syncthreads(); }
    if (t == 0) pB[b] = sdata[0];
}

// two waves: wave0 scans pA, wave1 scans pB; nb <= 128 (nb=98)
__global__ void scan_partials2_kernel(int* __restrict__ pA, int* __restrict__ pB, int nb) {
    int wv = threadIdx.x >> 6, lane = threadIdx.x & 63;
    int* p = wv ? pB : pA;
    int i0 = lane * 2, i1 = lane * 2 + 1;
    int v0 = (i0 < nb) ? p[i0] : 0;
    int v1 = (i1 < nb) ? p[i1] : 0;
    int sum = v0 + v1;
    int incl = sum;
    for (int ofs = 1; ofs < 64; ofs <<= 1) {
        int t = __shfl_up(incl, ofs);
        if (lane >= ofs) incl += t;
    }
    int run = incl - sum;   // exclusive base for this lane's segment
    if (i0 < nb) p[i0] = run;
    if (i1 < nb) p[i1] = run + v0;
}

__global__ void scan_final2_kernel(const int* __restrict__ dA, const int* __restrict__ pA,
                                   int* __restrict__ rp,
                                   const int* __restrict__ dB, const int* __restrict__ pB,
                                   int* __restrict__ remap,
                                   int* __restrict__ flist, int* __restrict__ nf_dev, int n) {
    __shared__ int sthread[256];
    int b = blockIdx.x, t = threadIdx.x;
    int base = b * SCAN_CHUNK;
    {
        int v[4]; int sum = 0;
#pragma unroll
        for (int i = 0; i < 4; ++i) { int idx = base + 4 * t + i; v[i] = (idx < n) ? dA[idx] : 0; sum += v[i]; }
        sthread[t] = sum; __syncthreads();
        for (int ofs = 1; ofs < 256; ofs <<= 1) {
            int val = (t >= ofs) ? sthread[t - ofs] : 0;
            __syncthreads(); sthread[t] += val; __syncthreads();
        }
        int run = sthread[t] - sum + pA[b];
#pragma unroll
        for (int i = 0; i < 4; ++i) { int idx = base + 4 * t + i; if (idx < n) rp[idx] = run; run += v[i]; }
        __syncthreads();
    }
    {
        int v[4]; int sum = 0;
#pragma unroll
        for (int i = 0; i < 4; ++i) { int idx = base + 4 * t + i; v[i] = (idx < n) ? dB[idx] : 0; sum += v[i]; }
        sthread[t] = sum; __syncthreads();
        for (int ofs = 1; ofs < 256; ofs <<= 1) {
            int val = (t >= ofs) ? sthread[t - ofs] : 0;
            __syncthreads(); sthread[t] += val; __syncthreads();
        }
        int run = sthread[t] - sum + pB[b];
#pragma unroll
        for (int i = 0; i < 4; ++i) {
            int idx = base + 4 * t + i;
            if (idx < n) {
                remap[idx] = run;
                if (v[i] && run < NFCAP) flist[run] = idx;
                if (idx == n - 1) *nf_dev = min(run + v[i], NFCAP);
            }
            run += v[i];
        }
    }
}

// ---- fill_csr body: LDS bitmask flags + 4 edges/thread split-phase ----
__device__ __forceinline__ void fill_csr_body(const int* __restrict__ src,
                                              const int* __restrict__ dst,
                                              const unsigned int* __restrict__ bitsG,
                                              int* __restrict__ rp, int* __restrict__ col,
                                              int E, int n, int fblk,
                                              unsigned char* smem) {
    unsigned int* bm = (unsigned int*)smem;   // 12.5 KB of the union
    int tid = threadIdx.x;
    int nw = (n + 31) >> 5;
    for (int i = tid; i < nw; i += 256) bm[i] = bitsG[i];
    __syncthreads();

    int t = fblk * 256 + tid;
    int e0 = t * 4;
    if (e0 + 3 < E) {
        int4 dv = *(const int4*)(dst + e0);
        int4 sv = *(const int4*)(src + e0);
        const int* dp = (const int*)&dv;
        const int* sp = (const int*)&sv;
        // phase 1: 4 independent LDS bit tests (no global txns)
        bool f[4];
#pragma unroll
        for (int i = 0; i < 4; ++i) {
            int d = dp[i];
            f[i] = ((unsigned)d < (unsigned)n) && ((unsigned)sp[i] < (unsigned)n)
                   && ((bm[d >> 5] >> (d & 31)) & 1u);
        }
        // phase 2: issue all 4 atomics; results not consumed -> in flight together
        int pos[4];
#pragma unroll
        for (int i = 0; i < 4; ++i) {
            pos[i] = -1;
            if (f[i]) pos[i] = atomicAdd(&rp[dp[i]], 1);
        }
        // phase 3: one wait, 4 independent scattered stores
#pragma unroll
        for (int i = 0; i < 4; ++i) {
            if (f[i] && (unsigned)pos[i] < (unsigned)E) col[pos[i]] = sp[i];
        }
    } else {
        for (int e = e0; e < E; ++e) {
            int d = dst[e], s = src[e];
            if ((unsigned)d < (unsigned)n && (unsigned)s < (unsigned)n &&
                ((bm[d >> 5] >> (d & 31)) & 1u)) {
                int pos = atomicAdd(&rp[d], 1);
                if ((unsigned)pos < (unsigned)E) col[pos] = s;
            }
        }
    }
}

// ---- Wt staging helper: [128][128] fp16, group g of row n at g^(n&15) ----
__device__ __forceinline__ void stage_wt(const float* __restrict__ W, _Float16* Wt, int tid) {
#pragma unroll
    for (int i = 0; i < 8; ++i) {
        int j = tid + 256 * i;        // 0..2047
        int nr = j & 127;
        int k8 = j >> 7;              // 0..15
        f16x8 v;
#pragma unroll
        for (int kk = 0; kk < 8; ++kk)
            v[kk] = (_Float16)W[(k8 * 8 + kk) * F_DIM + nr];
        *(f16x8*)&Wt[nr * F_DIM + ((k8 ^ (nr & 15)) * 8)] = v;
    }
}

// ---- MFMA fp16 GEMM body (fp32 input): outh = f16(X @ W) ----
// 256 threads = 4 waves, 64 rows/block. Wt in LDS (swizzled); A-frags
// from global X; passthrough rows >= U -> pout from the same regs.
__device__ __forceinline__ void gemm_mfma_body(const float* __restrict__ X,
                                               const float* __restrict__ W,
                                               _Float16* __restrict__ outh,
                                               float* __restrict__ pout,
                                               int nrows, int rowBase,
                                               unsigned char* smem) {
    _Float16* Wt = (_Float16*)smem;
    int tid = threadIdx.x;
    stage_wt(W, Wt, tid);
    __syncthreads();

    int w = tid >> 6;
    int lane = tid & 63;
    int m = lane & 15;
    int quad = lane >> 4;
    int row = rowBase + w * 16 + m;
    bool rv = row < nrows;

    // A-fragments: 8 floats per kc straight from global, convert to fp16.
    f16x8 a0, a1, a2, a3;
    {
        const float* xr = X + (size_t)row * F_DIM;
        float* pr = (pout != nullptr && rv && row >= U_USERS)
                        ? pout + (size_t)row * F_DIM : nullptr;
#pragma unroll
        for (int kc = 0; kc < 4; ++kc) {
            float4 lo = make_float4(0.f, 0.f, 0.f, 0.f);
            float4 hi = lo;
            if (rv) {
                lo = ((const float4*)(xr + kc * 32 + quad * 8))[0];
                hi = ((const float4*)(xr + kc * 32 + quad * 8))[1];
            }
            if (pr) {
                ((float4*)(pr + kc * 32 + quad * 8))[0] = lo;
                ((float4*)(pr + kc * 32 + quad * 8))[1] = hi;
            }
            f16x8 av;
            av[0] = (_Float16)lo.x; av[1] = (_Float16)lo.y;
            av[2] = (_Float16)lo.z; av[3] = (_Float16)lo.w;
            av[4] = (_Float16)hi.x; av[5] = (_Float16)hi.y;
            av[6] = (_Float16)hi.z; av[7] = (_Float16)hi.w;
            if (kc == 0) a0 = av; else if (kc == 1) a1 = av;
            else if (kc == 2) a2 = av; else a3 = av;
        }
    }

    f32x4 acc[8];
#pragma unroll
    for (int i = 0; i < 8; ++i) acc[i] = (f32x4){0.f, 0.f, 0.f, 0.f};

#pragma unroll
    for (int kc = 0; kc < 4; ++kc) {
        f16x8 a = (kc == 0) ? a0 : (kc == 1) ? a1 : (kc == 2) ? a2 : a3;
#pragma unroll
        for (int ct = 0; ct < 8; ++ct) {
            f16x8 b = *(const f16x8*)&Wt[(ct * 16 + m) * F_DIM +
                                         (((kc * 4 + quad) ^ m) * 8)];
            acc[ct] = __builtin_amdgcn_mfma_f32_16x16x32_f16(a, b, acc[ct], 0, 0, 0);
        }
    }

#pragma unroll
    for (int ct = 0; ct < 8; ++ct) {
#pragma unroll
        for (int reg = 0; reg < 4; ++reg) {
            int r = rowBase + w * 16 + quad * 4 + reg;
            if (r < nrows)
                outh[(size_t)r * F_DIM + ct * 16 + m] = (_Float16)acc[ct][reg];
        }
    }
}

// ---- MFMA fp16 GEMM body (fp16 input rows, layer 2) ----
// A-frags: one 16B f16x8 load per kc from Xh (workspace, slack past
// nrows inside NFCAP -- garbage rows only affect discarded C rows).
__device__ __forceinline__ void gemm_mfma_body_h(const _Float16* __restrict__ Xh,
                                                 const float* __restrict__ W,
                                                 _Float16* __restrict__ outh,
                                                 int nrows, int rowBase,
                                                 unsigned char* smem) {
    _Float16* Wt = (_Float16*)smem;
    int tid = threadIdx.x;
    stage_wt(W, Wt, tid);
    __syncthreads();

    int w = tid >> 6;
    int lane = tid & 63;
    int m = lane & 15;
    int quad = lane >> 4;
    int row = rowBase + w * 16 + m;
    const _Float16* xr = Xh + (size_t)row * F_DIM;

    f32x4 acc[8];
#pragma unroll
    for (int i = 0; i < 8; ++i) acc[i] = (f32x4){0.f, 0.f, 0.f, 0.f};

#pragma unroll
    for (int kc = 0; kc < 4; ++kc) {
        f16x8 a = *(const f16x8*)(xr + kc * 32 + quad * 8);
#pragma unroll
        for (int ct = 0; ct < 8; ++ct) {
            f16x8 b = *(const f16x8*)&Wt[(ct * 16 + m) * F_DIM +
                                         (((kc * 4 + quad) ^ m) * 8)];
            acc[ct] = __builtin_amdgcn_mfma_f32_16x16x32_f16(a, b, acc[ct], 0, 0, 0);
        }
    }

#pragma unroll
    for (int ct = 0; ct < 8; ++ct) {
#pragma unroll
        for (int reg = 0; reg < 4; ++reg) {
            int r = rowBase + w * 16 + quad * 4 + reg;
            if (r < nrows)
                outh[(size_t)r * F_DIM + ct * 16 + m] = (_Float16)acc[ct][reg];
        }
    }
}

// ---- fused dispatch: Bresenham-interleaved roles ----
__global__ __launch_bounds__(256) void gemm_fill_kernel(const float* __restrict__ X,
                                                        const float* __restrict__ W,
                                                        _Float16* __restrict__ outh,
                                                        float* __restrict__ pout, int nrows,
                                                        int gemmBlocks, int totalBlocks,
                                                        const int* __restrict__ src,
                                                        const int* __restrict__ dst,
                                                        const unsigned int* __restrict__ bitsG,
                                                        int* __restrict__ rp,
                                                        int* __restrict__ col, int E, int n) {
    __shared__ __align__(16) unsigned char smem[SMEM_BYTES];   // 32 KB union
    int b = blockIdx.x;
    long long g = gemmBlocks, T = totalBlocks;
    int before = (int)((long long)b * g / T);        // gemm blocks in [0,b)
    int after  = (int)(((long long)b + 1) * g / T);
    if (after > before) {
        gemm_mfma_body(X, W, outh, pout, nrows, before * 64, smem);
    } else {
        fill_csr_body(src, dst, bitsG, rp, col, E, n, b - before, smem);
    }
}

__global__ __launch_bounds__(256) void gemm_f16_dyn_kernel(const _Float16* __restrict__ Xh,
                                                           const float* __restrict__ W,
                                                           _Float16* __restrict__ outh,
                                                           const int* __restrict__ nrows_p) {
    __shared__ __align__(16) unsigned char smem[SMEM_BYTES];
    int nrows = *nrows_p;
    int rowBase = blockIdx.x * 64;
    if (rowBase >= nrows) return;
    gemm_mfma_body_h(Xh, W, outh, nrows, rowBase, smem);
}

// ---- layer-1 gather over compact frontier rows (fp16 rows, fp32 accum) ----
// 8-way MLP: 8 independent broadcast row-reads in flight per wave.
__global__ __launch_bounds__(256) void gather_l1_kernel(const _Float16* __restrict__ xwh,
                                                        const float* __restrict__ inv,
                                                        const int* __restrict__ rp,
                                                        const int* __restrict__ col,
                                                        const int* __restrict__ flist,
                                                        const int* __restrict__ nf_p,
                                                        const float* __restrict__ b,
                                                        _Float16* __restrict__ h1c) {
    int ci = blockIdx.x * 4 + (threadIdx.x >> 6);
    if (ci >= *nf_p) return;
    int lane = threadIdx.x & 63;
    int node = flist[ci];
    int start = (node == 0) ? 0 : rp[node - 1];
    int end = rp[node];

    float accx = 0.f, accy = 0.f;
    for (int base = start; base < end; base += 64) {
        int j = base + lane;
        int s_l = 0; float c_l = 0.f;
        if (j < end) { s_l = col[j]; c_l = inv[s_l]; }
        int cnt = min(64, end - base);
        int i = 0;
        for (; i + 8 <= cnt; i += 8) {
            int ss[8]; float ff[8]; f16x2 vv[8];
#pragma unroll
            for (int u = 0; u < 8; ++u) { ss[u] = __shfl(s_l, i + u); ff[u] = __shfl(c_l, i + u); }
#pragma unroll
            for (int u = 0; u < 8; ++u) vv[u] = ((const f16x2*)(xwh + (size_t)ss[u] * F_DIM))[lane];
#pragma unroll
            for (int u = 0; u < 8; ++u) { accx += (float)vv[u][0] * ff[u]; accy += (float)vv[u][1] * ff[u]; }
        }
        for (; i + 4 <= cnt; i += 4) {
            int ss[4]; float ff[4]; f16x2 vv[4];
#pragma unroll
            for (int u = 0; u < 4; ++u) { ss[u] = __shfl(s_l, i + u); ff[u] = __shfl(c_l, i + u); }
#pragma unroll
            for (int u = 0; u < 4; ++u) vv[u] = ((const f16x2*)(xwh + (size_t)ss[u] * F_DIM))[lane];
#pragma unroll
            for (int u = 0; u < 4; ++u) { accx += (float)vv[u][0] * ff[u]; accy += (float)vv[u][1] * ff[u]; }
        }
        for (; i < cnt; ++i) {
            int s0 = __shfl(s_l, i); float f0 = __shfl(c_l, i);
            f16x2 v0 = ((const f16x2*)(xwh + (size_t)s0 * F_DIM))[lane];
            accx += (float)v0[0] * f0;
            accy += (float)v0[1] * f0;
        }
    }

    float ivd = inv[node];
    f16x2 self = ((const f16x2*)(xwh + (size_t)node * F_DIM))[lane];
    float vx = accx * ivd + (float)self[0] * ivd * ivd + b[lane * 2];
    float vy = accy * ivd + (float)self[1] * ivd * ivd + b[lane * 2 + 1];
    vx = vx > 0.f ? vx : expf(vx) - 1.f;
    vy = vy > 0.f ? vy : expf(vy) - 1.f;
    f16x2 o; o[0] = (_Float16)vx; o[1] = (_Float16)vy;
    ((f16x2*)(h1c + (size_t)ci * F_DIM))[lane] = o;
}

// ---- layer-2 gather over rows [0,U) (fp16 compact rows), 8-way MLP ----
__global__ __launch_bounds__(256) void gather_l2_kernel(const _Float16* __restrict__ xwc,
                                                        const float* __restrict__ inv,
                                                        const int* __restrict__ rp,
                                                        const int* __restrict__ col,
                                                        const int* __restrict__ remap,
                                                        const float* __restrict__ b,
                                                        float* __restrict__ out) {
    int node = blockIdx.x * 4 + (threadIdx.x >> 6);
    if (node >= U_USERS) return;
    int lane = threadIdx.x & 63;
    int start = (node == 0) ? 0 : rp[node - 1];
    int end = rp[node];

    float accx = 0.f, accy = 0.f;
    for (int base = start; base < end; base += 64) {
        int j = base + lane;
        int r_l = 0; float c_l = 0.f;
        if (j < end) { int s = col[j]; c_l = inv[s]; r_l = remap[s]; }
        int cnt = min(64, end - base);
        int i = 0;
        for (; i + 8 <= cnt; i += 8) {
            int rr[8]; float ff[8]; f16x2 vv[8];
#pragma unroll
            for (int u = 0; u < 8; ++u) { rr[u] = __shfl(r_l, i + u); ff[u] = __shfl(c_l, i + u); }
#pragma unroll
            for (int u = 0; u < 8; ++u) vv[u] = ((const f16x2*)(xwc + (size_t)rr[u] * F_DIM))[lane];
#pragma unroll
            for (int u = 0; u < 8; ++u) { accx += (float)vv[u][0] * ff[u]; accy += (float)vv[u][1] * ff[u]; }
        }
        for (; i + 4 <= cnt; i += 4) {
            int rr[4]; float ff[4]; f16x2 vv[4];
#pragma unroll
            for (int u = 0; u < 4; ++u) { rr[u] = __shfl(r_l, i + u); ff[u] = __shfl(c_l, i + u); }
#pragma unroll
            for (int u = 0; u < 4; ++u) vv[u] = ((const f16x2*)(xwc + (size_t)rr[u] * F_DIM))[lane];
#pragma unroll
            for (int u = 0; u < 4; ++u) { accx += (float)vv[u][0] * ff[u]; accy += (float)vv[u][1] * ff[u]; }
        }
        for (; i < cnt; ++i) {
            int r0 = __shfl(r_l, i); float f0 = __shfl(c_l, i);
            f16x2 v0 = ((const f16x2*)(xwc + (size_t)r0 * F_DIM))[lane];
            accx += (float)v0[0] * f0;
            accy += (float)v0[1] * f0;
        }
    }

    float ivd = inv[node];
    f16x2 self = ((const f16x2*)(xwc + (size_t)node * F_DIM))[lane];  // remap[node]==node for node<U
    float vx = accx * ivd + (float)self[0] * ivd * ivd + b[lane * 2];
    float vy = accy * ivd + (float)self[1] * ivd * ivd + b[lane * 2 + 1];
    vx = vx > 0.f ? vx : expf(vx) - 1.f;
    vy = vy > 0.f ? vy : expf(vy) - 1.f;
    ((float2*)(out + (size_t)node * F_DIM))[lane] = make_float2(vx, vy);
}

extern "C" void kernel_launch(void* const* d_in, const int* in_sizes, int n_in,
                              void* d_out, int out_size, void* d_ws, size_t ws_size,
                              hipStream_t stream) {
    const float* x  = (const float*)d_in[0];
    const int*   ei = (const int*)d_in[1];   // [2, E] int32
    const float* W1 = (const float*)d_in[2];
    const float* b1 = (const float*)d_in[3];
    const float* W2 = (const float*)d_in[4];
    const float* b2 = (const float*)d_in[5];
    float* out = (float*)d_out;

    int n = in_sizes[0] / F_DIM;   // 100000
    int E = in_sizes[1] / 2;       // 3200000
    const int* srcI = ei;
    const int* dstI = ei + E;

    // workspace layout (~90 MB); h1c region kept at fp32 size, used as fp16
    _Float16* xwh = (_Float16*)d_ws;                 // n*128 halfs (xw1 / xwc, 25.6MB)
    _Float16* h1c = xwh + (size_t)n * F_DIM;         // NFCAP*128 halfs (region sized 2x)
    float* inv   = (float*)(h1c + (size_t)NFCAP * F_DIM * 2);  // n f
    int* fr      = (int*)(inv + n);                  // n
    int* degF    = fr + n;                           // n
    int* remap   = degF + n;                         // n
    int* rp      = remap + n;                        // n
    int* flist   = rp + n;                           // NFCAP
    int* pA      = flist + NFCAP;                    // 1024
    int* pB      = pA + 1024;                        // 1024
    int* nf_dev  = pB + 1024;                        // 1 (+pad)
    int* col     = nf_dev + 16;                      // E
    unsigned int* partialH = (unsigned int*)(col + E);  // NCHUNK*PSLICE*SW
    unsigned int* bitsG = partialH + (size_t)NCHUNK * PSLICE * SW;  // BMW words

    int nb = (n + SCAN_CHUNK - 1) / SCAN_CHUNK;      // 98

    hipMemsetAsync(fr, 0, (size_t)n * sizeof(int), stream);
    hipMemsetAsync(bitsG, 0, (size_t)BMW * sizeof(unsigned int), stream);

    hist_kernel<<<NCHUNK * PSLICE, 1024, 0, stream>>>(srcI, dstI, partialH, fr, E, n);
    reduce_prep_kernel<<<(NCHUNK * SW + 255) / 256, 256, 0, stream>>>(partialH, inv, fr, degF, bitsG, n);

    scan_reduce2_kernel<<<nb, 256, 0, stream>>>(degF, fr, pA, pB, n);
    scan_partials2_kernel<<<1, 128, 0, stream>>>(pA, pB, nb);
    scan_final2_kernel<<<nb, 256, 0, stream>>>(degF, pA, rp, fr, pB, remap, flist, nf_dev, n);

    // fused, role-interleaved: every CU holds a mix of fill (scatter
    // latency) and gemm (MFMA/stream) blocks at all times.
    int fillBlocks = (E / 4 + 255) / 256;    // 3125
    int gemmBlocks = (n + 63) / 64;          // 1563
    gemm_fill_kernel<<<fillBlocks + gemmBlocks, 256, 0, stream>>>(
        x, W1, xwh, out, n, gemmBlocks, fillBlocks + gemmBlocks,
        srcI, dstI, bitsG, rp, col, E, n);

    gather_l1_kernel<<<(NFCAP + 3) / 4, 256, 0, stream>>>(xwh, inv, rp, col, flist, nf_dev, b1, h1c);

    // layer 2: compact MFMA GEMM (nf rows, fp16 input), gather over U rows
    gemm_f16_dyn_kernel<<<(NFCAP + 63) / 64, 256, 0, stream>>>(h1c, W2, xwh, nf_dev);
    gather_l2_kernel<<<(U_USERS + 3) / 4, 256, 0, stream>>>(xwh, inv, rp, col, remap, b2, out);
}

// Round 9
// 268.903 us; speedup vs baseline: 1.1522x; 1.0393x over previous
//
#include <hip/hip_runtime.h>

// GCNLinkPredictor: 2-layer GCN, N=100000, E=3.2M, F=128, U=1000.
// R16: dispatch-count collapse (11 -> 7).
//   R15 post-mortem: kernel-body arithmetic accounts for only ~90us of
//   the ~190us non-fused time => ~80-110us is launch gaps (11 dispatches
//   x ~5-10us). Fix:
//   (a) reduce_prep + 3 scan kernels -> ONE decoupled-lookback kernel
//       (prep_scan): 49 blocks x 1024 thr, 2 nodes/thread, partial-sums
//       read directly (degF round-trip deleted), dual scan packed in one
//       u64 LDS scan, windowed 64-lane lookback (49 < 64 -> 1 round).
//   (b) bitsG built block-locally (whole words) -> memset deleted.
//   (c) fr + desc zeroed by one tiny kernel -> 2 memsets -> 1 dispatch.
// Carried: role-interleaved gemm+fill fusion (R14), Wt-in-LDS swizzled
// gemm + X->regs (R13), LDS bitmask flags (R10), split-phase atomics
// (R9), hist int4 (R8), passthrough fusion (R8), 8-way MLP gathers +
// fp16 h1c (R15).

#define F_DIM 128
#define U_USERS 1000
#define NFCAP 48000     // frontier cap (expected ~33K)
#define NCHUNK 3        // node-space chunks for histogram
#define SBIN 40960      // nodes per chunk (3*40960 >= 100000)
#define SW (SBIN / 2)   // packed words per chunk (2 x u16 per word)
#define PSLICE 85       // edge slices per chunk -> 255 blocks
#define BMW 3136        // frontier bitmask words (= NBPS*64)
#define SMEM_BYTES 32768   // Wt [128][128] fp16 (>= bitmask 12544)
#define NBPS 49         // prep_scan blocks (49*2048 >= 100000)

using f16x8 = __attribute__((ext_vector_type(8))) _Float16;
using f16x2 = __attribute__((ext_vector_type(2))) _Float16;
using f32x4 = __attribute__((ext_vector_type(4))) float;

// ---- zero fr + lookback descriptors (replaces 2 memsets) ----
__global__ __launch_bounds__(256) void zero_kernel(int* __restrict__ fr,
                                                   unsigned long long* __restrict__ desc,
                                                   int n) {
    int t = blockIdx.x * 256 + threadIdx.x;
    int n4 = n >> 2;
    if (t < n4) ((int4*)fr)[t] = make_int4(0, 0, 0, 0);
    if (t < (n & 3)) fr[(n & ~3) + t] = 0;
    if (t < NBPS) desc[t] = 0ull;
}

// ---- histogram: LDS packed counters, no global atomics ----
__global__ __launch_bounds__(1024) void hist_kernel(const int* __restrict__ src,
                                                    const int* __restrict__ dst,
                                                    unsigned int* __restrict__ partial,
                                                    int* __restrict__ fr, int E, int n) {
    __shared__ unsigned int h[SW];   // 80 KB
    int tid = threadIdx.x;
    int c = blockIdx.x % NCHUNK;
    int p = blockIdx.x / NCHUNK;
    for (int i = tid; i < SW; i += 1024) h[i] = 0u;
    __syncthreads();

    int lo = c * SBIN;
    int hi = lo + SBIN;
    int len = (E + PSLICE - 1) / PSLICE;
    int base = p * len;
    int end = min(E, base + len);
    int e = base + tid * 4;
    for (; e + 3 < end; e += 4096) {
        int4 dv = *(const int4*)(dst + e);
#pragma unroll
        for (int i = 0; i < 4; ++i) {
            int d = ((const int*)&dv)[i];
            if ((unsigned)d < (unsigned)n) {
                if (d >= lo && d < hi) {
                    int local = d - lo;
                    atomicAdd(&h[local >> 1], 1u << ((local & 1) << 4));
                }
                if (c == 0 && d < U_USERS) {
                    int s = src[e + i];
                    if ((unsigned)s < (unsigned)n) fr[s] = 1;
                }
            }
        }
    }
    for (; e < end; ++e) {   // tail (rare)
        int d = dst[e];
        if ((unsigned)d < (unsigned)n) {
            if (d >= lo && d < hi) {
                int local = d - lo;
                atomicAdd(&h[local >> 1], 1u << ((local & 1) << 4));
            }
            if (c == 0 && d < U_USERS) {
                int s = src[e];
                if ((unsigned)s < (unsigned)n) fr[s] = 1;
            }
        }
    }
    __syncthreads();
    unsigned int* outp = partial + ((size_t)(c * PSLICE + p)) * SW;
    for (int i = tid; i < SW; i += 1024) outp[i] = h[i];
}

// ---- merged prep + dual scan (decoupled lookback, one dispatch) ----
// 49 blocks x 1024 threads, thread t owns nodes (2t, 2t+1) of its block.
// Produces: inv, rp (excl deg-prefix over frontier degs), remap (excl
// frontier-count prefix), flist, nf_dev, bitsG. Packed u64 scan value:
// A(deg)<<20 | B(frontier flag); A<=3.3M<2^28, B<=100K<2^20 -> no carry.
__global__ __launch_bounds__(1024) void prep_scan_kernel(
    const unsigned int* __restrict__ partial, const int* __restrict__ fr,
    float* __restrict__ inv, int* __restrict__ rp, int* __restrict__ remap,
    int* __restrict__ flist, int* __restrict__ nf_dev,
    unsigned int* __restrict__ bitsG, unsigned long long* __restrict__ desc, int n) {
    __shared__ unsigned long long ss[1024];
    __shared__ unsigned int bmw[64];
    __shared__ unsigned long long spre;
    int b = blockIdx.x, t = threadIdx.x;
    int i0 = b * 2048 + t * 2;

    // deg for both nodes from histogram partials (packed u16 pairs)
    unsigned a0 = 0, a1 = 0;
    {
        int c = i0 / SBIN;
        int w = (i0 - c * SBIN) >> 1;
        const unsigned int* bp = partial + (size_t)c * PSLICE * SW + w;
#pragma unroll 5
        for (int p = 0; p < PSLICE; ++p) {
            unsigned v = bp[(size_t)p * SW];
            a0 += v & 0xFFFFu; a1 += v >> 16;
        }
    }
    bool in0 = i0 < n, in1 = i0 + 1 < n;
    int fv0 = 0, fv1 = 0;
    if (in1) { int2 f2 = *(const int2*)(fr + i0); fv0 = f2.x; fv1 = f2.y; }
    else if (in0) fv0 = fr[i0];
    int isf0 = (in0 && ((i0 < U_USERS) || fv0)) ? 1 : 0;
    int isf1 = (in1 && ((i0 + 1 < U_USERS) || fv1)) ? 1 : 0;
    unsigned d0 = isf0 ? a0 : 0u, d1 = isf1 ? a1 : 0u;

    if (in1) *(float2*)(inv + i0) = make_float2(rsqrtf((float)a0 + 1.f),
                                                rsqrtf((float)a1 + 1.f));
    else if (in0) inv[i0] = rsqrtf((float)a0 + 1.f);

    // frontier bitmask: block owns 64 whole words (2048 nodes)
    if (t < 64) bmw[t] = 0u;
    __syncthreads();
    unsigned pbits = (unsigned)isf0 | ((unsigned)isf1 << 1);
    if (pbits) atomicOr(&bmw[(t * 2) >> 5], pbits << ((t * 2) & 31));
    __syncthreads();
    if (t < 64) bitsG[b * 64 + t] = bmw[t];

    // packed inclusive scan over 1024 per-thread pair-sums
    unsigned long long myv = ((unsigned long long)(d0 + d1) << 20) |
                             (unsigned)(isf0 + isf1);
    ss[t] = myv;
    __syncthreads();
    for (int ofs = 1; ofs < 1024; ofs <<= 1) {
        unsigned long long v = (t >= ofs) ? ss[t - ofs] : 0ull;
        __syncthreads(); ss[t] += v; __syncthreads();
    }
    unsigned long long total = ss[1023];

    // publish aggregate; windowed lookback (<= 48 predecessors < 64 lanes)
    if (t == 0) atomicExch(&desc[b], (total << 1) | 1ull);
    if (t < 64) {
        int pblk = b - 1 - t;
        unsigned long long v = 0ull;
        if (pblk >= 0) {
            unsigned long long d;
            do { d = atomicAdd(&desc[pblk], 0ull); } while (!(d & 1ull));
            v = d >> 1;
        }
#pragma unroll
        for (int o = 32; o > 0; o >>= 1) v += __shfl_down(v, o);
        if (t == 0) spre = v;
    }
    __syncthreads();

    unsigned long long ex = spre + ss[t] - myv;   // exclusive prefix at node i0
    int rp0 = (int)(ex >> 20), rm0 = (int)(ex & 0xFFFFFu);
    unsigned long long ex1 = ex + ((((unsigned long long)d0) << 20) | (unsigned)isf0);
    int rp1 = (int)(ex1 >> 20), rm1 = (int)(ex1 & 0xFFFFFu);
    if (in1) {
        *(int2*)(rp + i0) = make_int2(rp0, rp1);
        *(int2*)(remap + i0) = make_int2(rm0, rm1);
    } else if (in0) { rp[i0] = rp0; remap[i0] = rm0; }
    if (isf0 && rm0 < NFCAP) flist[rm0] = i0;
    if (isf1 && rm1 < NFCAP) flist[rm1] = i0 + 1;
    if (in0 && i0 == n - 1) *nf_dev = min(rp0 * 0 + rm0 + isf0, NFCAP);
    if (in1 && i0 + 1 == n - 1) *nf_dev = min(rm1 + isf1, NFCAP);
}

// ---- fill_csr body: LDS bitmask flags + 4 edges/thread split-phase ----
__device__ __forceinline__ void fill_csr_body(const int* __restrict__ src,
                                              const int* __restrict__ dst,
                                              const unsigned int* __restrict__ bitsG,
                                              int* __restrict__ rp, int* __restrict__ col,
                                              int E, int n, int fblk,
                                              unsigned char* smem) {
    unsigned int* bm = (unsigned int*)smem;   // 12.5 KB of the union
    int tid = threadIdx.x;
    int nw = (n + 31) >> 5;
    for (int i = tid; i < nw; i += 256) bm[i] = bitsG[i];
    __syncthreads();

    int t = fblk * 256 + tid;
    int e0 = t * 4;
    if (e0 + 3 < E) {
        int4 dv = *(const int4*)(dst + e0);
        int4 sv = *(const int4*)(src + e0);
        const int* dp = (const int*)&dv;
        const int* sp = (const int*)&sv;
        bool f[4];
#pragma unroll
        for (int i = 0; i < 4; ++i) {
            int d = dp[i];
            f[i] = ((unsigned)d < (unsigned)n) && ((unsigned)sp[i] < (unsigned)n)
                   && ((bm[d >> 5] >> (d & 31)) & 1u);
        }
        int pos[4];
#pragma unroll
        for (int i = 0; i < 4; ++i) {
            pos[i] = -1;
            if (f[i]) pos[i] = atomicAdd(&rp[dp[i]], 1);
        }
#pragma unroll
        for (int i = 0; i < 4; ++i) {
            if (f[i] && (unsigned)pos[i] < (unsigned)E) col[pos[i]] = sp[i];
        }
    } else {
        for (int e = e0; e < E; ++e) {
            int d = dst[e], s = src[e];
            if ((unsigned)d < (unsigned)n && (unsigned)s < (unsigned)n &&
                ((bm[d >> 5] >> (d & 31)) & 1u)) {
                int pos = atomicAdd(&rp[d], 1);
                if ((unsigned)pos < (unsigned)E) col[pos] = s;
            }
        }
    }
}

// ---- Wt staging helper: [128][128] fp16, group g of row n at g^(n&15) ----
__device__ __forceinline__ void stage_wt(const float* __restrict__ W, _Float16* Wt, int tid) {
#pragma unroll
    for (int i = 0; i < 8; ++i) {
        int j = tid + 256 * i;        // 0..2047
        int nr = j & 127;
        int k8 = j >> 7;              // 0..15
        f16x8 v;
#pragma unroll
        for (int kk = 0; kk < 8; ++kk)
            v[kk] = (_Float16)W[(k8 * 8 + kk) * F_DIM + nr];
        *(f16x8*)&Wt[nr * F_DIM + ((k8 ^ (nr & 15)) * 8)] = v;
    }
}

// ---- MFMA fp16 GEMM body (fp32 input): outh = f16(X @ W) ----
__device__ __forceinline__ void gemm_mfma_body(const float* __restrict__ X,
                                               const float* __restrict__ W,
                                               _Float16* __restrict__ outh,
                                               float* __restrict__ pout,
                                               int nrows, int rowBase,
                                               unsigned char* smem) {
    _Float16* Wt = (_Float16*)smem;
    int tid = threadIdx.x;
    stage_wt(W, Wt, tid);
    __syncthreads();

    int w = tid >> 6;
    int lane = tid & 63;
    int m = lane & 15;
    int quad = lane >> 4;
    int row = rowBase + w * 16 + m;
    bool rv = row < nrows;

    f16x8 a0, a1, a2, a3;
    {
        const float* xr = X + (size_t)row * F_DIM;
        float* pr = (pout != nullptr && rv && row >= U_USERS)
                        ? pout + (size_t)row * F_DIM : nullptr;
#pragma unroll
        for (int kc = 0; kc < 4; ++kc) {
            float4 lo = make_float4(0.f, 0.f, 0.f, 0.f);
            float4 hi = lo;
            if (rv) {
                lo = ((const float4*)(xr + kc * 32 + quad * 8))[0];
                hi = ((const float4*)(xr + kc * 32 + quad * 8))[1];
            }
            if (pr) {
                ((float4*)(pr + kc * 32 + quad * 8))[0] = lo;
                ((float4*)(pr + kc * 32 + quad * 8))[1] = hi;
            }
            f16x8 av;
            av[0] = (_Float16)lo.x; av[1] = (_Float16)lo.y;
            av[2] = (_Float16)lo.z; av[3] = (_Float16)lo.w;
            av[4] = (_Float16)hi.x; av[5] = (_Float16)hi.y;
            av[6] = (_Float16)hi.z; av[7] = (_Float16)hi.w;
            if (kc == 0) a0 = av; else if (kc == 1) a1 = av;
            else if (kc == 2) a2 = av; else a3 = av;
        }
    }

    f32x4 acc[8];
#pragma unroll
    for (int i = 0; i < 8; ++i) acc[i] = (f32x4){0.f, 0.f, 0.f, 0.f};

#pragma unroll
    for (int kc = 0; kc < 4; ++kc) {
        f16x8 a = (kc == 0) ? a0 : (kc == 1) ? a1 : (kc == 2) ? a2 : a3;
#pragma unroll
        for (int ct = 0; ct < 8; ++ct) {
            f16x8 b = *(const f16x8*)&Wt[(ct * 16 + m) * F_DIM +
                                         (((kc * 4 + quad) ^ m) * 8)];
            acc[ct] = __builtin_amdgcn_mfma_f32_16x16x32_f16(a, b, acc[ct], 0, 0, 0);
        }
    }

#pragma unroll
    for (int ct = 0; ct < 8; ++ct) {
#pragma unroll
        for (int reg = 0; reg < 4; ++reg) {
            int r = rowBase + w * 16 + quad * 4 + reg;
            if (r < nrows)
                outh[(size_t)r * F_DIM + ct * 16 + m] = (_Float16)acc[ct][reg];
        }
    }
}

// ---- MFMA fp16 GEMM body (fp16 input rows, layer 2) ----
__device__ __forceinline__ void gemm_mfma_body_h(const _Float16* __restrict__ Xh,
                                                 const float* __restrict__ W,
                                                 _Float16* __restrict__ outh,
                                                 int nrows, int rowBase,
                                                 unsigned char* smem) {
    _Float16* Wt = (_Float16*)smem;
    int tid = threadIdx.x;
    stage_wt(W, Wt, tid);
    __syncthreads();

    int w = tid >> 6;
    int lane = tid & 63;
    int m = lane & 15;
    int quad = lane >> 4;
    int row = rowBase + w * 16 + m;
    const _Float16* xr = Xh + (size_t)row * F_DIM;

    f32x4 acc[8];
#pragma unroll
    for (int i = 0; i < 8; ++i) acc[i] = (f32x4){0.f, 0.f, 0.f, 0.f};

#pragma unroll
    for (int kc = 0; kc < 4; ++kc) {
        f16x8 a = *(const f16x8*)(xr + kc * 32 + quad * 8);
#pragma unroll
        for (int ct = 0; ct < 8; ++ct) {
            f16x8 b = *(const f16x8*)&Wt[(ct * 16 + m) * F_DIM +
                                         (((kc * 4 + quad) ^ m) * 8)];
            acc[ct] = __builtin_amdgcn_mfma_f32_16x16x32_f16(a, b, acc[ct], 0, 0, 0);
        }
    }

#pragma unroll
    for (int ct = 0; ct < 8; ++ct) {
#pragma unroll
        for (int reg = 0; reg < 4; ++reg) {
            int r = rowBase + w * 16 + quad * 4 + reg;
            if (r < nrows)
                outh[(size_t)r * F_DIM + ct * 16 + m] = (_Float16)acc[ct][reg];
        }
    }
}

// ---- fused dispatch: Bresenham-interleaved roles ----
__global__ __launch_bounds__(256) void gemm_fill_kernel(const float* __restrict__ X,
                                                        const float* __restrict__ W,
                                                        _Float16* __restrict__ outh,
                                                        float* __restrict__ pout, int nrows,
                                                        int gemmBlocks, int totalBlocks,
                                                        const int* __restrict__ src,
                                                        const int* __restrict__ dst,
                                                        const unsigned int* __restrict__ bitsG,
                                                        int* __restrict__ rp,
                                                        int* __restrict__ col, int E, int n) {
    __shared__ __align__(16) unsigned char smem[SMEM_BYTES];   // 32 KB union
    int b = blockIdx.x;
    long long g = gemmBlocks, T = totalBlocks;
    int before = (int)((long long)b * g / T);
    int after  = (int)(((long long)b + 1) * g / T);
    if (after > before) {
        gemm_mfma_body(X, W, outh, pout, nrows, before * 64, smem);
    } else {
        fill_csr_body(src, dst, bitsG, rp, col, E, n, b - before, smem);
    }
}

__global__ __launch_bounds__(256) void gemm_f16_dyn_kernel(const _Float16* __restrict__ Xh,
                                                           const float* __restrict__ W,
                                                           _Float16* __restrict__ outh,
                                                           const int* __restrict__ nrows_p) {
    __shared__ __align__(16) unsigned char smem[SMEM_BYTES];
    int nrows = *nrows_p;
    int rowBase = blockIdx.x * 64;
    if (rowBase >= nrows) return;
    gemm_mfma_body_h(Xh, W, outh, nrows, rowBase, smem);
}

// ---- layer-1 gather over compact frontier rows (fp16 rows, fp32 accum) ----
__global__ __launch_bounds__(256) void gather_l1_kernel(const _Float16* __restrict__ xwh,
                                                        const float* __restrict__ inv,
                                                        const int* __restrict__ rp,
                                                        const int* __restrict__ col,
                                                        const int* __restrict__ flist,
                                                        const int* __restrict__ nf_p,
                                                        const float* __restrict__ b,
                                                        _Float16* __restrict__ h1c) {
    int ci = blockIdx.x * 4 + (threadIdx.x >> 6);
    if (ci >= *nf_p) return;
    int lane = threadIdx.x & 63;
    int node = flist[ci];
    int start = (node == 0) ? 0 : rp[node - 1];
    int end = rp[node];

    float accx = 0.f, accy = 0.f;
    for (int base = start; base < end; base += 64) {
        int j = base + lane;
        int s_l = 0; float c_l = 0.f;
        if (j < end) { s_l = col[j]; c_l = inv[s_l]; }
        int cnt = min(64, end - base);
        int i = 0;
        for (; i + 8 <= cnt; i += 8) {
            int ss[8]; float ff[8]; f16x2 vv[8];
#pragma unroll
            for (int u = 0; u < 8; ++u) { ss[u] = __shfl(s_l, i + u); ff[u] = __shfl(c_l, i + u); }
#pragma unroll
            for (int u = 0; u < 8; ++u) vv[u] = ((const f16x2*)(xwh + (size_t)ss[u] * F_DIM))[lane];
#pragma unroll
            for (int u = 0; u < 8; ++u) { accx += (float)vv[u][0] * ff[u]; accy += (float)vv[u][1] * ff[u]; }
        }
        for (; i + 4 <= cnt; i += 4) {
            int ss[4]; float ff[4]; f16x2 vv[4];
#pragma unroll
            for (int u = 0; u < 4; ++u) { ss[u] = __shfl(s_l, i + u); ff[u] = __shfl(c_l, i + u); }
#pragma unroll
            for (int u = 0; u < 4; ++u) vv[u] = ((const f16x2*)(xwh + (size_t)ss[u] * F_DIM))[lane];
#pragma unroll
            for (int u = 0; u < 4; ++u) { accx += (float)vv[u][0] * ff[u]; accy += (float)vv[u][1] * ff[u]; }
        }
        for (; i < cnt; ++i) {
            int s0 = __shfl(s_l, i); float f0 = __shfl(c_l, i);
            f16x2 v0 = ((const f16x2*)(xwh + (size_t)s0 * F_DIM))[lane];
            accx += (float)v0[0] * f0;
            accy += (float)v0[1] * f0;
        }
    }

    float ivd = inv[node];
    f16x2 self = ((const f16x2*)(xwh + (size_t)node * F_DIM))[lane];
    float vx = accx * ivd + (float)self[0] * ivd * ivd + b[lane * 2];
    float vy = accy * ivd + (float)self[1] * ivd * ivd + b[lane * 2 + 1];
    vx = vx > 0.f ? vx : expf(vx) - 1.f;
    vy = vy > 0.f ? vy : expf(vy) - 1.f;
    f16x2 o; o[0] = (_Float16)vx; o[1] = (_Float16)vy;
    ((f16x2*)(h1c + (size_t)ci * F_DIM))[lane] = o;
}

// ---- layer-2 gather over rows [0,U) (fp16 compact rows), 8-way MLP ----
__global__ __launch_bounds__(256) void gather_l2_kernel(const _Float16* __restrict__ xwc,
                                                        const float* __restrict__ inv,
                                                        const int* __restrict__ rp,
                                                        const int* __restrict__ col,
                                                        const int* __restrict__ remap,
                                                        const float* __restrict__ b,
                                                        float* __restrict__ out) {
    int node = blockIdx.x * 4 + (threadIdx.x >> 6);
    if (node >= U_USERS) return;
    int lane = threadIdx.x & 63;
    int start = (node == 0) ? 0 : rp[node - 1];
    int end = rp[node];

    float accx = 0.f, accy = 0.f;
    for (int base = start; base < end; base += 64) {
        int j = base + lane;
        int r_l = 0; float c_l = 0.f;
        if (j < end) { int s = col[j]; c_l = inv[s]; r_l = remap[s]; }
        int cnt = min(64, end - base);
        int i = 0;
        for (; i + 8 <= cnt; i += 8) {
            int rr[8]; float ff[8]; f16x2 vv[8];
#pragma unroll
            for (int u = 0; u < 8; ++u) { rr[u] = __shfl(r_l, i + u); ff[u] = __shfl(c_l, i + u); }
#pragma unroll
            for (int u = 0; u < 8; ++u) vv[u] = ((const f16x2*)(xwc + (size_t)rr[u] * F_DIM))[lane];
#pragma unroll
            for (int u = 0; u < 8; ++u) { accx += (float)vv[u][0] * ff[u]; accy += (float)vv[u][1] * ff[u]; }
        }
        for (; i + 4 <= cnt; i += 4) {
            int rr[4]; float ff[4]; f16x2 vv[4];
#pragma unroll
            for (int u = 0; u < 4; ++u) { rr[u] = __shfl(r_l, i + u); ff[u] = __shfl(c_l, i + u); }
#pragma unroll
            for (int u = 0; u < 4; ++u) vv[u] = ((const f16x2*)(xwc + (size_t)rr[u] * F_DIM))[lane];
#pragma unroll
            for (int u = 0; u < 4; ++u) { accx += (float)vv[u][0] * ff[u]; accy += (float)vv[u][1] * ff[u]; }
        }
        for (; i < cnt; ++i) {
            int r0 = __shfl(r_l, i); float f0 = __shfl(c_l, i);
            f16x2 v0 = ((const f16x2*)(xwc + (size_t)r0 * F_DIM))[lane];
            accx += (float)v0[0] * f0;
            accy += (float)v0[1] * f0;
        }
    }

    float ivd = inv[node];
    f16x2 self = ((const f16x2*)(xwc + (size_t)node * F_DIM))[lane];  // remap[node]==node for node<U
    float vx = accx * ivd + (float)self[0] * ivd * ivd + b[lane * 2];
    float vy = accy * ivd + (float)self[1] * ivd * ivd + b[lane * 2 + 1];
    vx = vx > 0.f ? vx : expf(vx) - 1.f;
    vy = vy > 0.f ? vy : expf(vy) - 1.f;
    ((float2*)(out + (size_t)node * F_DIM))[lane] = make_float2(vx, vy);
}

extern "C" void kernel_launch(void* const* d_in, const int* in_sizes, int n_in,
                              void* d_out, int out_size, void* d_ws, size_t ws_size,
                              hipStream_t stream) {
    const float* x  = (const float*)d_in[0];
    const int*   ei = (const int*)d_in[1];   // [2, E] int32
    const float* W1 = (const float*)d_in[2];
    const float* b1 = (const float*)d_in[3];
    const float* W2 = (const float*)d_in[4];
    const float* b2 = (const float*)d_in[5];
    float* out = (float*)d_out;

    int n = in_sizes[0] / F_DIM;   // 100000
    int E = in_sizes[1] / 2;       // 3200000
    const int* srcI = ei;
    const int* dstI = ei + E;

    // workspace layout (~75 MB); all region sizes divisible by 8 bytes
    _Float16* xwh = (_Float16*)d_ws;                 // n*128 halfs (25.6MB)
    _Float16* h1c = xwh + (size_t)n * F_DIM;         // NFCAP*128 halfs (12.3MB)
    float* inv   = (float*)(h1c + (size_t)NFCAP * F_DIM);  // n f
    int* fr      = (int*)(inv + n);                  // n
    int* remap   = fr + n;                           // n
    int* rp      = remap + n;                        // n
    int* flist   = rp + n;                           // NFCAP
    int* nf_dev  = flist + NFCAP;                    // 16 ints
    int* col     = nf_dev + 16;                      // E
    unsigned int* partialH = (unsigned int*)(col + E);  // NCHUNK*PSLICE*SW
    unsigned int* bitsG = partialH + (size_t)NCHUNK * PSLICE * SW;  // BMW words
    unsigned long long* desc = (unsigned long long*)(bitsG + BMW);  // NBPS u64

    zero_kernel<<<(n / 4 + 255) / 256, 256, 0, stream>>>(fr, desc, n);

    hist_kernel<<<NCHUNK * PSLICE, 1024, 0, stream>>>(srcI, dstI, partialH, fr, E, n);

    prep_scan_kernel<<<NBPS, 1024, 0, stream>>>(partialH, fr, inv, rp, remap,
                                                flist, nf_dev, bitsG, desc, n);

    // fused, role-interleaved gemm1 + fill_csr
    int fillBlocks = (E / 4 + 255) / 256;    // 3125
    int gemmBlocks = (n + 63) / 64;          // 1563
    gemm_fill_kernel<<<fillBlocks + gemmBlocks, 256, 0, stream>>>(
        x, W1, xwh, out, n, gemmBlocks, fillBlocks + gemmBlocks,
        srcI, dstI, bitsG, rp, col, E, n);

    gather_l1_kernel<<<(NFCAP + 3) / 4, 256, 0, stream>>>(xwh, inv, rp, col, flist, nf_dev, b1, h1c);

    // layer 2: compact MFMA GEMM (nf rows, fp16 input), gather over U rows
    gemm_f16_dyn_kernel<<<(NFCAP + 63) / 64, 256, 0, stream>>>(h1c, W2, xwh, nf_dev);
    gather_l2_kernel<<<(U_USERS + 3) / 4, 256, 0, stream>>>(xwh, inv, rp, col, remap, b2, out);
}